// Round 4
// baseline (514.261 us; speedup 1.0000x reference)
//
#include <hip/hip_runtime.h>

// Problem constants
#define SEQ  2048
#define NB   32
#define NS   512
#define MI   64   // M_IN
#define PO   64   // P_OUT
#define TB   64   // t-block
#define NTB  32   // SEQ/TB
#define CH   64   // i-chunk
#define NCH  8    // NS/CH
#define LDU  72   // u_b / Sw stride (ushort)
#define LDB  72   // Bm stride (ushort)
#define LDC  72   // Cm/Qm stride (ushort)
#define LDBU 68   // bu stride (float)
#define TB2  128  // h-impulse block
#define SG_LDA 72 // sgemm LDS stride (ushort)

typedef __attribute__((ext_vector_type(8))) __bf16 bf16x8;
typedef __attribute__((ext_vector_type(4))) float  floatx4;

__device__ inline unsigned short f2bf(float f) {
    unsigned u = __builtin_bit_cast(unsigned, f);
    u += 0x7fff + ((u >> 16) & 1);           // RNE
    return (unsigned short)(u >> 16);
}

__device__ inline float bf2f(unsigned short h) {
    unsigned u = ((unsigned)h) << 16;
    return __builtin_bit_cast(float, u);
}

__device__ inline bf16x8 cvt8(floatx4 lo, floatx4 hi) {
    bf16x8 r;
    r[0] = (__bf16)lo[0]; r[1] = (__bf16)lo[1]; r[2] = (__bf16)lo[2]; r[3] = (__bf16)lo[3];
    r[4] = (__bf16)hi[0]; r[5] = (__bf16)hi[1]; r[6] = (__bf16)hi[2]; r[7] = (__bf16)hi[3];
    return r;
}

// ---------------------------------------------------------------------------
// One-time fp32 -> bf16 conversion of B (512x64), C (64x512), D (64x64)
// ---------------------------------------------------------------------------
__global__ void __launch_bounds__(256) prep_kernel(
    const float* __restrict__ B, const float* __restrict__ C,
    const float* __restrict__ D, unsigned short* __restrict__ Bws,
    unsigned short* __restrict__ Cws, unsigned short* __restrict__ Dws) {
    const int idx = blockIdx.x * 256 + threadIdx.x;
    const int nB = NS * MI, nC = PO * NS, nD = PO * MI;
    if (idx < nB) Bws[idx] = f2bf(B[idx]);
    else if (idx < nB + nC) Cws[idx - nB] = f2bf(C[idx - nB]);
    else if (idx < nB + nC + nD) Dws[idx - nB - nC] = f2bf(D[idx - nB - nC]);
}

// ---------------------------------------------------------------------------
// u fp32 -> bf16, 8 elements per thread
// ---------------------------------------------------------------------------
__global__ void __launch_bounds__(256) uconv_kernel(const float* __restrict__ u,
                                                    unsigned short* __restrict__ ubf) {
    const size_t base = ((size_t)blockIdx.x * 256 + threadIdx.x) * 8;
    float4 f0 = *(const float4*)(u + base);
    float4 f1 = *(const float4*)(u + base + 4);
    unsigned short tmp[8];
    tmp[0] = f2bf(f0.x); tmp[1] = f2bf(f0.y); tmp[2] = f2bf(f0.z); tmp[3] = f2bf(f0.w);
    tmp[4] = f2bf(f1.x); tmp[5] = f2bf(f1.y); tmp[6] = f2bf(f1.z); tmp[7] = f2bf(f1.w);
    *(uint4*)(ubf + base) = *(uint4*)&tmp[0];
}

// ---------------------------------------------------------------------------
// BflatT[i][(j,m)] = B[i-j, m] (bf16, 0 for i<j).  512 x 4096, 4 MB.
// ---------------------------------------------------------------------------
__global__ void __launch_bounds__(256) bflatk_kernel(const float* __restrict__ B,
                                                     unsigned short* __restrict__ BflatT) {
    const int i = blockIdx.x;
    const int tid = threadIdx.x;
    for (int r = 0; r < 2; ++r) {
        const int id = tid + r * 256;          // 0..511
        const int j = id >> 3, q8 = (id & 7) * 8;
        unsigned short tmp[8];
        if (i >= j) {
            const float4 f0 = *(const float4*)(B + (size_t)(i - j) * MI + q8);
            const float4 f1 = *(const float4*)(B + (size_t)(i - j) * MI + q8 + 4);
            tmp[0] = f2bf(f0.x); tmp[1] = f2bf(f0.y); tmp[2] = f2bf(f0.z); tmp[3] = f2bf(f0.w);
            tmp[4] = f2bf(f1.x); tmp[5] = f2bf(f1.y); tmp[6] = f2bf(f1.z); tmp[7] = f2bf(f1.w);
        } else {
#pragma unroll
            for (int z = 0; z < 8; ++z) tmp[z] = 0;
        }
        *(uint4*)(BflatT + (size_t)i * 4096 + j * 64 + q8) = *(uint4*)&tmp[0];
    }
}

// ---------------------------------------------------------------------------
// qT[p][j] = sum_{i=j}^{NS-1} C[p,i] * a[NS-1-i+j]  — LDS-staged, lane-parallel
// over i with shuffle reduce. 32 WGs x 4 waves; each wave does 4 j x 64 p.
// ---------------------------------------------------------------------------
__global__ void __launch_bounds__(256) kq2_kernel(const unsigned short* __restrict__ Cws,
                                                  const float* __restrict__ a,
                                                  unsigned short* __restrict__ qT) {
    __shared__ unsigned short C_l[PO * NS];   // 64 KB
    __shared__ float a_l[NS];
    const int g = blockIdx.x, tid = threadIdx.x;
    for (int k = tid; k < PO * NS / 8; k += 256)
        ((uint4*)C_l)[k] = ((const uint4*)Cws)[k];
    for (int i = tid; i < NS; i += 256) a_l[i] = a[i];
    __syncthreads();
    const int w = tid >> 6, lane = tid & 63;
    const int wid = g * 4 + w;                 // 0..127
#pragma unroll
    for (int jj = 0; jj < 4; ++jj) {
        const int j = wid * 4 + jj;            // 0..511
        for (int p = 0; p < PO; ++p) {
            float acc = 0.f;
            for (int i = j + lane; i < NS; i += 64)
                acc += bf2f(C_l[p * NS + i]) * a_l[NS - 1 - i + j];
#pragma unroll
            for (int off = 32; off; off >>= 1) acc += __shfl_xor(acc, off);
            if (lane == 0) qT[(size_t)p * NS + j] = f2bf(acc);
        }
    }
}

// ---------------------------------------------------------------------------
// Impulse response of the scalar IIR (single WG; the only sequential part).
// ---------------------------------------------------------------------------
__global__ void __launch_bounds__(1024) himp_kernel(const float* __restrict__ a,
                                                    float* __restrict__ hbuf) {
    __shared__ float a_l[640];
    __shared__ float h_l[SEQ];
    __shared__ float part[16 * TB2];
    __shared__ float rhs_l[TB2];
    const int tid = threadIdx.x;
    const int kk = tid & 63, grp = tid >> 6;

    if (tid < NS) a_l[tid] = a[tid];
    if (tid >= NS && tid < 640) a_l[tid] = 0.f;
    __syncthreads();

    float a0r[32], a1r[32];
#pragma unroll
    for (int i = 0; i < 32; ++i) a0r[i] = a_l[kk + grp * 32 + i];
#pragma unroll
    for (int i = 0; i < 32; ++i) a1r[i] = a_l[kk + 64 + grp * 32 + i];

    if (tid < 64) {
        if (tid == 0) h_l[0] = 1.f;
        for (int t = 1; t < TB2; ++t) {
            float pr = 0.f;
            const int j1 = tid + 1, j2 = tid + 65;
            if (j1 <= t) pr += a_l[j1 - 1] * h_l[t - j1];
            if (j2 <= t) pr += a_l[j2 - 1] * h_l[t - j2];
#pragma unroll
            for (int off = 32; off; off >>= 1) pr += __shfl_xor(pr, off);
            if (tid == 0) h_l[t] = -pr;
        }
    }
    __syncthreads();

    for (int t0 = TB2; t0 < SEQ; t0 += TB2) {
        float acc0 = 0.f, acc1 = 0.f;
        if (grp * 32 < t0) {
#pragma unroll
            for (int m = 0; m < 8; ++m) {
                const float4 hv = *(const float4*)&h_l[t0 - grp * 32 - 4 - 4 * m];
                acc0 += a0r[4 * m + 0] * hv.w + a0r[4 * m + 1] * hv.z +
                        a0r[4 * m + 2] * hv.y + a0r[4 * m + 3] * hv.x;
                acc1 += a1r[4 * m + 0] * hv.w + a1r[4 * m + 1] * hv.z +
                        a1r[4 * m + 2] * hv.y + a1r[4 * m + 3] * hv.x;
            }
        }
        part[grp * TB2 + kk]      = acc0;
        part[grp * TB2 + kk + 64] = acc1;
        __syncthreads();
        if (tid < TB2) {
            float r = 0.f;
#pragma unroll
            for (int g = 0; g < 16; ++g) r += part[g * TB2 + tid];
            rhs_l[tid] = -r;
        }
        __syncthreads();
        if (tid < TB2) {
            float sv = 0.f;
            for (int j = 0; j <= tid; ++j) sv += h_l[j] * rhs_l[tid - j];
            h_l[t0 + tid] = sv;
        }
        __syncthreads();
    }
    for (int i = tid; i < SEQ; i += 1024) hbuf[i] = h_l[i];
}

// ---------------------------------------------------------------------------
// S-GEMM: S[(b,k), i] = sum_{(j,m)} BflatT[i][(j,m)] * u[b, k*64+63-j, m]
// M = 64 i per WG, N = 64 tiles per WG, K = 4096. Grid (8, 16).
// ---------------------------------------------------------------------------
__global__ void __launch_bounds__(256) sgemm_kernel(const unsigned short* __restrict__ ubf,
                                                    const unsigned short* __restrict__ BflatT,
                                                    float* __restrict__ Sbuf) {
    __shared__ unsigned short A_l[4 * 64 * SG_LDA];   // 36.8 KB
    __shared__ unsigned short U_l[4 * 64 * SG_LDA];
    const int ib = blockIdx.x, bp = blockIdx.y;
    const int tid = threadIdx.x, lane = tid & 63, w = tid >> 6;
    const int i0 = ib * 64;
    floatx4 acc[4];
#pragma unroll
    for (int ns = 0; ns < 4; ++ns) acc[ns] = (floatx4){0.f, 0.f, 0.f, 0.f};

    for (int jg = 0; jg < 16; ++jg) {
#pragma unroll
        for (int r = 0; r < 8; ++r) {
            const int id = tid + r * 256;        // 0..2047
            const int row = id >> 5;             // 0..63
            const int jj = (id >> 3) & 3, q8 = (id & 7) * 8;
            const int j = jg * 4 + jj;
            *(uint4*)&A_l[(jj * 64 + row) * SG_LDA + q8] =
                *(const uint4*)(BflatT + (size_t)(i0 + row) * 4096 + j * 64 + q8);
            const int bb = bp * 2 + (row >> 5), kkk = row & 31;
            *(uint4*)&U_l[(jj * 64 + row) * SG_LDA + q8] =
                *(const uint4*)(ubf + ((size_t)bb * SEQ + kkk * 64 + 63 - j) * MI + q8);
        }
        __syncthreads();
#pragma unroll
        for (int jj = 0; jj < 4; ++jj) {
#pragma unroll
            for (int mk = 0; mk < 2; ++mk) {
                const bf16x8 av = *(const bf16x8*)
                    &A_l[(jj * 64 + w * 16 + (lane & 15)) * SG_LDA + mk * 32 + ((lane >> 4) * 8)];
#pragma unroll
                for (int ns = 0; ns < 4; ++ns) {
                    const bf16x8 bv = *(const bf16x8*)
                        &U_l[(jj * 64 + ns * 16 + (lane & 15)) * SG_LDA + mk * 32 + ((lane >> 4) * 8)];
                    acc[ns] = __builtin_amdgcn_mfma_f32_16x16x32_bf16(av, bv, acc[ns], 0, 0, 0);
                }
            }
        }
        __syncthreads();
    }
#pragma unroll
    for (int ns = 0; ns < 4; ++ns) {
        const int n = ns * 16 + (lane & 15);
        const int bb = bp * 2 + (n >> 5), kkk = n & 31;
        float* dst = Sbuf + ((size_t)bb * NTB + kkk) * NS + i0 + w * 16 + ((lane >> 4) * 4);
        *(floatx4*)dst = acc[ns];
    }
}

// ---------------------------------------------------------------------------
// Block-carry scan: R_{k+1}[i] = S_k[i] + R_k[i-TB], R_0 = 0.
// ---------------------------------------------------------------------------
__global__ void __launch_bounds__(256) scan_kernel(const float* __restrict__ Sbuf,
                                                   float* __restrict__ Rbuf) {
    __shared__ float S_l[NTB * NS];
    __shared__ float Rc[2][NS];
    const int b = blockIdx.x, tid = threadIdx.x;
    const float4* src = (const float4*)(Sbuf + (size_t)b * NTB * NS);
    float4* dst = (float4*)S_l;
    for (int k = tid; k < NTB * NS / 4; k += 256) dst[k] = src[k];
    if (tid < 128) ((float4*)Rc[0])[tid] = make_float4(0.f, 0.f, 0.f, 0.f);
    __syncthreads();
    int cur = 0;
    for (int k = 0; k < NTB; ++k) {
        if (tid < 128) {
            const int i0 = tid * 4;
            float4 r = ((const float4*)Rc[cur])[tid];
            *(float4*)(Rbuf + ((size_t)b * NTB + k) * NS + i0) = r;
            float4 s = *(const float4*)&S_l[k * NS + i0];
            float4 rp = (i0 >= TB) ? *(const float4*)&Rc[cur][i0 - TB]
                                   : make_float4(0.f, 0.f, 0.f, 0.f);
            float4 nv = make_float4(s.x + rp.x, s.y + rp.y, s.z + rp.z, s.w + rp.w);
            *(float4*)&Rc[cur ^ 1][i0] = nv;
        }
        __syncthreads();
        cur ^= 1;
    }
}

// ---------------------------------------------------------------------------
// ytile (MFMA): per (t-block, batch): Bu chunks via MFMA, uniform-t diagonal
// cumsum (conflict-free), y = C*G + D*u, emit f.
// ---------------------------------------------------------------------------
__global__ void __launch_bounds__(256, 3) ytile_kernel(
    const unsigned short* __restrict__ ubf, const unsigned short* __restrict__ Bws,
    const unsigned short* __restrict__ Cws, const unsigned short* __restrict__ Dws,
    const float* __restrict__ Rbuf, float* __restrict__ fbuf, float* __restrict__ y) {
    __shared__ unsigned short u_b[TB * LDU];
    __shared__ unsigned short Bm[CH * LDB];
    __shared__ unsigned short Cm[PO * LDC];
    __shared__ float bu[TB * LDBU];
    __shared__ float colBuf[2][TB];

    const int blk = blockIdx.x, b = blockIdx.y;
    const int t0 = blk * TB;
    const int tid = threadIdx.x;
    const int lane = tid & 63, w = tid >> 6;

    // stage u tile (bf16, pre-converted)
#pragma unroll
    for (int r = 0; r < 2; ++r) {
        const int id = tid + r * 256;
        const int t = id >> 3, q8 = (id & 7) * 8;
        *(uint4*)&u_b[t * LDU + q8] =
            *(const uint4*)(ubf + ((size_t)b * SEQ + t0 + t) * MI + q8);
    }
    if (tid < TB) colBuf[0][tid] = 0.f;

    floatx4 accY[4];
#pragma unroll
    for (int nt = 0; nt < 4; ++nt) accY[nt] = (floatx4){0.f, 0.f, 0.f, 0.f};
    __syncthreads();

    int cur = 0;
    for (int ch = 0; ch < NCH; ++ch) {
        {
            const int r = tid >> 2, c0 = (tid & 3) * 16;
            const uint4* bs = (const uint4*)(Bws + (size_t)(ch * CH + r) * MI + c0);
            uint4 v0 = bs[0], v1 = bs[1];
            *(uint4*)&Bm[r * LDB + c0]     = v0;
            *(uint4*)&Bm[r * LDB + c0 + 8] = v1;
            const uint4* cs = (const uint4*)(Cws + (size_t)r * NS + ch * CH + c0);
            uint4 w0 = cs[0], w1 = cs[1];
            *(uint4*)&Cm[r * LDC + c0]     = w0;
            *(uint4*)&Cm[r * LDC + c0 + 8] = w1;
        }
        __syncthreads();

        // phase A: Bu chunk
        {
            const bf16x8 a0 = *(const bf16x8*)&Bm[(w * 16 + (lane & 15)) * LDB + ((lane >> 4) * 8)];
            const bf16x8 a1 = *(const bf16x8*)&Bm[(w * 16 + (lane & 15)) * LDB + 32 + ((lane >> 4) * 8)];
#pragma unroll
            for (int nt = 0; nt < 4; ++nt) {
                const int t = nt * 16 + (lane & 15);
                bf16x8 b0 = *(const bf16x8*)&u_b[t * LDU + ((lane >> 4) * 8)];
                bf16x8 b1 = *(const bf16x8*)&u_b[t * LDU + 32 + ((lane >> 4) * 8)];
                floatx4 d = {0.f, 0.f, 0.f, 0.f};
                d = __builtin_amdgcn_mfma_f32_16x16x32_bf16(a0, b0, d, 0, 0, 0);
                d = __builtin_amdgcn_mfma_f32_16x16x32_bf16(a1, b1, d, 0, 0, 0);
                *(floatx4*)&bu[t * LDBU + w * 16 + ((lane >> 4) * 4)] = d;
            }
        }
        __syncthreads();

        // diagonal walk — UNIFORM t across lanes (conflict-free LDS)
        const int nxt = cur ^ 1;
        if (tid < 127) {
            const int cl = tid - 63;              // local diag i - t: -63..63
            float carry;
            if (cl < 0) carry = colBuf[cur][-cl - 1];
            else {
                const int gi = ch * CH + cl;
                carry = (gi >= 1) ? Rbuf[((size_t)b * NTB + blk) * NS + gi - 1] : 0.f;
            }
            for (int t = 0; t < TB; ++t) {
                const int il = cl + t;
                if (il >= 0 && il < CH) {
                    carry += bu[t * LDBU + il];
                    bu[t * LDBU + il] = carry;
                    if (il == CH - 1) {
                        if (ch == NCH - 1) fbuf[(size_t)b * SEQ + t0 + t] = carry;
                        else if (t < TB - 1) colBuf[nxt][t] = carry;
                    }
                }
            }
        }
        __syncthreads();

        // phase B: accY += C[:,chunk] * G[chunk]
        {
            const bf16x8 ca0 = *(const bf16x8*)&Cm[(w * 16 + (lane & 15)) * LDC + ((lane >> 4) * 8)];
            const bf16x8 ca1 = *(const bf16x8*)&Cm[(w * 16 + (lane & 15)) * LDC + 32 + ((lane >> 4) * 8)];
#pragma unroll
            for (int nt = 0; nt < 4; ++nt) {
                const int t  = nt * 16 + (lane & 15);
                const int k0 = (lane >> 4) * 8;
                floatx4 g0 = *(const floatx4*)&bu[t * LDBU + k0];
                floatx4 g1 = *(const floatx4*)&bu[t * LDBU + k0 + 4];
                floatx4 h0 = *(const floatx4*)&bu[t * LDBU + 32 + k0];
                floatx4 h1 = *(const floatx4*)&bu[t * LDBU + 32 + k0 + 4];
                accY[nt] = __builtin_amdgcn_mfma_f32_16x16x32_bf16(ca0, cvt8(g0, g1), accY[nt], 0, 0, 0);
                accY[nt] = __builtin_amdgcn_mfma_f32_16x16x32_bf16(ca1, cvt8(h0, h1), accY[nt], 0, 0, 0);
            }
        }
        __syncthreads();
        cur = nxt;
    }

    // epilogue: += D*u, store y
    {
        const int r = tid >> 2, c0 = (tid & 3) * 16;
        const uint4* ds = (const uint4*)(Dws + (size_t)r * MI + c0);
        uint4 v0 = ds[0], v1 = ds[1];
        *(uint4*)&Cm[r * LDC + c0]     = v0;
        *(uint4*)&Cm[r * LDC + c0 + 8] = v1;
    }
    __syncthreads();
    const bf16x8 da0 = *(const bf16x8*)&Cm[(w * 16 + (lane & 15)) * LDC + ((lane >> 4) * 8)];
    const bf16x8 da1 = *(const bf16x8*)&Cm[(w * 16 + (lane & 15)) * LDC + 32 + ((lane >> 4) * 8)];
#pragma unroll
    for (int nt = 0; nt < 4; ++nt) {
        const int t = nt * 16 + (lane & 15);
        bf16x8 b0 = *(const bf16x8*)&u_b[t * LDU + ((lane >> 4) * 8)];
        bf16x8 b1 = *(const bf16x8*)&u_b[t * LDU + 32 + ((lane >> 4) * 8)];
        accY[nt] = __builtin_amdgcn_mfma_f32_16x16x32_bf16(da0, b0, accY[nt], 0, 0, 0);
        accY[nt] = __builtin_amdgcn_mfma_f32_16x16x32_bf16(da1, b1, accY[nt], 0, 0, 0);
        const int p0 = w * 16 + ((lane >> 4) * 4);
        *(floatx4*)(y + ((size_t)b * SEQ + t0 + t) * PO + p0) = accY[nt];
    }
}

// ---------------------------------------------------------------------------
// s[b][t] = sum_{j=0..t} h[j] f[b][t-j]
// ---------------------------------------------------------------------------
__global__ void __launch_bounds__(256) sconv_kernel(const float* __restrict__ fbuf,
                                                    const float* __restrict__ hbuf,
                                                    float* __restrict__ sbuf) {
    __shared__ float f_l[SEQ];
    __shared__ float h_lc[SEQ + 8];
    __shared__ float part[4][TB];
    const int blk = blockIdx.x, b = blockIdx.y, tid = threadIdx.x;
    const int t0 = blk * TB;
    const int len = t0 + TB;
    {
        const float4* fs = (const float4*)(fbuf + (size_t)b * SEQ);
        const float4* hs = (const float4*)hbuf;
        for (int i = tid; i < len / 4; i += 256) {
            ((float4*)f_l)[i] = fs[i];
            ((float4*)h_lc)[i] = hs[i];
        }
    }
    __syncthreads();
    const int dt = tid & 63, grp = tid >> 6;
    const int t = t0 + dt;
    float acc = 0.f;
    for (int j4 = grp * 4; j4 <= t; j4 += 16) {
        const float4 hv = *(const float4*)&h_lc[j4];
        if (j4 + 0 <= t) acc += hv.x * f_l[t - j4 - 0];
        if (j4 + 1 <= t) acc += hv.y * f_l[t - j4 - 1];
        if (j4 + 2 <= t) acc += hv.z * f_l[t - j4 - 2];
        if (j4 + 3 <= t) acc += hv.w * f_l[t - j4 - 3];
    }
    part[grp][dt] = acc;
    __syncthreads();
    if (tid < TB) {
        sbuf[(size_t)b * SEQ + t0 + tid] =
            part[0][tid] + part[1][tid] + part[2][tid] + part[3][tid];
    }
}

// ---------------------------------------------------------------------------
// corr (MFMA): y[b,t,p] -= sum_j qT[p][j] * s[b, t-1-j]
// ---------------------------------------------------------------------------
__global__ void __launch_bounds__(256) corr_kernel(
    const float* __restrict__ sbuf, const unsigned short* __restrict__ qT,
    float* __restrict__ y) {
    __shared__ float s_l[NS + TB];
    __shared__ unsigned short Qm[PO * LDC];
    __shared__ unsigned short Sw[TB * LDU];
    const int blk = blockIdx.x, b = blockIdx.y, tid = threadIdx.x;
    const int t0 = blk * TB;
    const int lane = tid & 63, w = tid >> 6;
    for (int idx = tid; idx < NS + TB; idx += 256) {
        const int t = t0 - NS + idx;
        s_l[idx] = (t >= 0) ? sbuf[(size_t)b * SEQ + t] : 0.f;
    }
    floatx4 acc[4];
#pragma unroll
    for (int nt = 0; nt < 4; ++nt) acc[nt] = (floatx4){0.f, 0.f, 0.f, 0.f};
    __syncthreads();

    for (int ch = 0; ch < NCH; ++ch) {
        const int r = tid >> 2, c0 = (tid & 3) * 16;
        {
            const uint4* qs = (const uint4*)(qT + (size_t)r * NS + ch * CH + c0);
            uint4 v0 = qs[0], v1 = qs[1];
            *(uint4*)&Qm[r * LDC + c0]     = v0;
            *(uint4*)&Qm[r * LDC + c0 + 8] = v1;
        }
        {
            unsigned short tmp[16];
            const int base = 511 + r - ch * CH - c0;
#pragma unroll
            for (int jj = 0; jj < 16; ++jj) tmp[jj] = f2bf(s_l[base - jj]);
            *(uint4*)&Sw[r * LDU + c0]     = *(uint4*)&tmp[0];
            *(uint4*)&Sw[r * LDU + c0 + 8] = *(uint4*)&tmp[8];
        }
        __syncthreads();
        const bf16x8 qa0 = *(const bf16x8*)&Qm[(w * 16 + (lane & 15)) * LDC + ((lane >> 4) * 8)];
        const bf16x8 qa1 = *(const bf16x8*)&Qm[(w * 16 + (lane & 15)) * LDC + 32 + ((lane >> 4) * 8)];
#pragma unroll
        for (int nt = 0; nt < 4; ++nt) {
            const int t = nt * 16 + (lane & 15);
            bf16x8 s0 = *(const bf16x8*)&Sw[t * LDU + ((lane >> 4) * 8)];
            bf16x8 s1 = *(const bf16x8*)&Sw[t * LDU + 32 + ((lane >> 4) * 8)];
            acc[nt] = __builtin_amdgcn_mfma_f32_16x16x32_bf16(qa0, s0, acc[nt], 0, 0, 0);
            acc[nt] = __builtin_amdgcn_mfma_f32_16x16x32_bf16(qa1, s1, acc[nt], 0, 0, 0);
        }
        __syncthreads();
    }
#pragma unroll
    for (int nt = 0; nt < 4; ++nt) {
        const int t = nt * 16 + (lane & 15);
        const int p0 = w * 16 + ((lane >> 4) * 4);
        float* yp = y + ((size_t)b * SEQ + t0 + t) * PO + p0;
        floatx4 old = *(const floatx4*)yp;
        *(floatx4*)yp = old - acc[nt];
    }
}

// ---------------------------------------------------------------------------
extern "C" void kernel_launch(void* const* d_in, const int* in_sizes, int n_in,
                              void* d_out, int out_size, void* d_ws,
                              size_t ws_size, hipStream_t stream) {
    const float* u  = (const float*)d_in[0];
    const float* a  = (const float*)d_in[1];
    const float* B  = (const float*)d_in[2];
    const float* Cm = (const float*)d_in[3];
    const float* Dm = (const float*)d_in[4];
    float* y = (float*)d_out;

    char* ws = (char*)d_ws;
    unsigned short* Bws = (unsigned short*)ws;                  ws += NS * MI * 2;
    unsigned short* Cws = (unsigned short*)ws;                  ws += PO * NS * 2;
    unsigned short* Dws = (unsigned short*)ws;                  ws += PO * MI * 2;
    unsigned short* qTw = (unsigned short*)ws;                  ws += PO * NS * 2;
    unsigned short* ubf = (unsigned short*)ws;                  ws += (size_t)NB * SEQ * MI * 2;
    unsigned short* Bft = (unsigned short*)ws;                  ws += (size_t)NS * 4096 * 2;
    float* Sbuf = (float*)ws;                                   ws += (size_t)NB * NTB * NS * 4;
    float* Rbuf = (float*)ws;                                   ws += (size_t)NB * NTB * NS * 4;
    float* fbuf = (float*)ws;                                   ws += (size_t)NB * SEQ * 4;
    float* sbuf = (float*)ws;                                   ws += (size_t)NB * SEQ * 4;
    float* hbuf = (float*)ws;                                   // 2048 floats  (~17.5 MB total)

    prep_kernel<<<dim3(272), dim3(256), 0, stream>>>(B, Cm, Dm, Bws, Cws, Dws);
    uconv_kernel<<<dim3(2048), dim3(256), 0, stream>>>(u, ubf);
    bflatk_kernel<<<dim3(512), dim3(256), 0, stream>>>(B, Bft);
    kq2_kernel<<<dim3(32), dim3(256), 0, stream>>>(Cws, a, qTw);
    himp_kernel<<<dim3(1), dim3(1024), 0, stream>>>(a, hbuf);
    sgemm_kernel<<<dim3(8, 16), dim3(256), 0, stream>>>(ubf, Bft, Sbuf);
    scan_kernel<<<dim3(NB), dim3(256), 0, stream>>>(Sbuf, Rbuf);
    ytile_kernel<<<dim3(NTB, NB), dim3(256), 0, stream>>>(
        ubf, Bws, Cws, Dws, Rbuf, fbuf, y);
    sconv_kernel<<<dim3(NTB, NB), dim3(256), 0, stream>>>(fbuf, hbuf, sbuf);
    corr_kernel<<<dim3(NTB, NB), dim3(256), 0, stream>>>(sbuf, qTw, y);
}

// Round 5
// 408.570 us; speedup vs baseline: 1.2587x; 1.2587x over previous
//
#include <hip/hip_runtime.h>

// Problem constants
#define SEQ  2048
#define NB   32
#define NS   512
#define MI   64   // M_IN
#define PO   64   // P_OUT
#define TB   64   // t-block
#define NTB  32   // SEQ/TB
#define CH   64   // i-chunk
#define NCH  8    // NS/CH
#define LDU  72   // u_b / Sw stride (ushort)
#define LDBU 68   // bu stride (float)
#define SG_LDA 72 // sgemm LDS stride (ushort)

typedef __attribute__((ext_vector_type(8))) __bf16 bf16x8;
typedef __attribute__((ext_vector_type(4))) float  floatx4;

__device__ inline unsigned short f2bf(float f) {
    unsigned u = __builtin_bit_cast(unsigned, f);
    u += 0x7fff + ((u >> 16) & 1);           // RNE
    return (unsigned short)(u >> 16);
}

__device__ inline bf16x8 cvt8(floatx4 lo, floatx4 hi) {
    bf16x8 r;
    r[0] = (__bf16)lo[0]; r[1] = (__bf16)lo[1]; r[2] = (__bf16)lo[2]; r[3] = (__bf16)lo[3];
    r[4] = (__bf16)hi[0]; r[5] = (__bf16)hi[1]; r[6] = (__bf16)hi[2]; r[7] = (__bf16)hi[3];
    return r;
}

// ---------------------------------------------------------------------------
// Fused prep: [0,2048) u->bf16 | [2048,2560) BflatT | [2560,2624) q
// | [2624,2896) B/C/D -> bf16
// ---------------------------------------------------------------------------
__global__ void __launch_bounds__(256) prep_all_kernel(
    const float* __restrict__ u, const float* __restrict__ B,
    const float* __restrict__ C, const float* __restrict__ D,
    const float* __restrict__ a,
    unsigned short* __restrict__ ubf, unsigned short* __restrict__ BflatT,
    unsigned short* __restrict__ Bws, unsigned short* __restrict__ Cws,
    unsigned short* __restrict__ Dws, unsigned short* __restrict__ qT) {
    __shared__ float a_ext[1024];
    const int bx = blockIdx.x, tid = threadIdx.x;
    if (bx < 2048) {                       // ---- uconv
        const size_t base = ((size_t)bx * 256 + tid) * 8;
        float4 f0 = *(const float4*)(u + base);
        float4 f1 = *(const float4*)(u + base + 4);
        unsigned short tmp[8];
        tmp[0] = f2bf(f0.x); tmp[1] = f2bf(f0.y); tmp[2] = f2bf(f0.z); tmp[3] = f2bf(f0.w);
        tmp[4] = f2bf(f1.x); tmp[5] = f2bf(f1.y); tmp[6] = f2bf(f1.z); tmp[7] = f2bf(f1.w);
        *(uint4*)(ubf + base) = *(uint4*)&tmp[0];
    } else if (bx < 2560) {                // ---- BflatT[i][(j,m)] = B[i-j,m]
        const int i = bx - 2048;
        for (int r = 0; r < 2; ++r) {
            const int id = tid + r * 256;
            const int j = id >> 3, q8 = (id & 7) * 8;
            unsigned short tmp[8];
            if (i >= j) {
                const float4 f0 = *(const float4*)(B + (size_t)(i - j) * MI + q8);
                const float4 f1 = *(const float4*)(B + (size_t)(i - j) * MI + q8 + 4);
                tmp[0] = f2bf(f0.x); tmp[1] = f2bf(f0.y); tmp[2] = f2bf(f0.z); tmp[3] = f2bf(f0.w);
                tmp[4] = f2bf(f1.x); tmp[5] = f2bf(f1.y); tmp[6] = f2bf(f1.z); tmp[7] = f2bf(f1.w);
            } else {
#pragma unroll
                for (int z = 0; z < 8; ++z) tmp[z] = 0;
            }
            *(uint4*)(BflatT + (size_t)i * 4096 + j * 64 + q8) = *(uint4*)&tmp[0];
        }
    } else if (bx < 2624) {                // ---- q: qT[p][j]
        const int p = bx - 2560;
        for (int x = tid; x < 1024; x += 256) a_ext[x] = (x < NS) ? a[x] : 0.f;
        __syncthreads();
        const int j0 = tid, j1 = tid + 256;
        float acc0 = 0.f, acc1 = 0.f;
        const float4* crow = (const float4*)(C + (size_t)p * NS);
        for (int i4 = 0; i4 < NS / 4; ++i4) {
            const float4 cv = crow[i4];
            const int base = 511 - i4 * 4;
            acc0 += cv.x * a_ext[base + j0]     + cv.y * a_ext[base - 1 + j0] +
                    cv.z * a_ext[base - 2 + j0] + cv.w * a_ext[base - 3 + j0];
            acc1 += cv.x * a_ext[base + j1]     + cv.y * a_ext[base - 1 + j1] +
                    cv.z * a_ext[base - 2 + j1] + cv.w * a_ext[base - 3 + j1];
        }
        qT[(size_t)p * NS + j0] = f2bf(acc0);
        qT[(size_t)p * NS + j1] = f2bf(acc1);
    } else {                               // ---- B/C/D bf16 cvt
        const int idx = (bx - 2624) * 256 + tid;
        const int nB = NS * MI, nC = PO * NS, nD = PO * MI;
        if (idx < nB) Bws[idx] = f2bf(B[idx]);
        else if (idx < nB + nC) Cws[idx - nB] = f2bf(C[idx - nB]);
        else if (idx < nB + nC + nD) Dws[idx - nB - nC] = f2bf(D[idx - nB - nC]);
    }
}

// ---------------------------------------------------------------------------
// S-GEMM: S[(b,k), i] = sum_{(j,m)} BflatT[i][(j,m)] * u[b, k*64+63-j, m]
// ---------------------------------------------------------------------------
__global__ void __launch_bounds__(256) sgemm_kernel(const unsigned short* __restrict__ ubf,
                                                    const unsigned short* __restrict__ BflatT,
                                                    float* __restrict__ Sbuf) {
    __shared__ unsigned short A_l[4 * 64 * SG_LDA];
    __shared__ unsigned short U_l[4 * 64 * SG_LDA];
    const int ib = blockIdx.x, bp = blockIdx.y;
    const int tid = threadIdx.x, lane = tid & 63, w = tid >> 6;
    const int i0 = ib * 64;
    floatx4 acc[4];
#pragma unroll
    for (int ns = 0; ns < 4; ++ns) acc[ns] = (floatx4){0.f, 0.f, 0.f, 0.f};

    for (int jg = 0; jg < 16; ++jg) {
#pragma unroll
        for (int r = 0; r < 8; ++r) {
            const int id = tid + r * 256;
            const int row = id >> 5;
            const int jj = (id >> 3) & 3, q8 = (id & 7) * 8;
            const int j = jg * 4 + jj;
            *(uint4*)&A_l[(jj * 64 + row) * SG_LDA + q8] =
                *(const uint4*)(BflatT + (size_t)(i0 + row) * 4096 + j * 64 + q8);
            const int bb = bp * 2 + (row >> 5), kkk = row & 31;
            *(uint4*)&U_l[(jj * 64 + row) * SG_LDA + q8] =
                *(const uint4*)(ubf + ((size_t)bb * SEQ + kkk * 64 + 63 - j) * MI + q8);
        }
        __syncthreads();
#pragma unroll
        for (int jj = 0; jj < 4; ++jj) {
#pragma unroll
            for (int mk = 0; mk < 2; ++mk) {
                const bf16x8 av = *(const bf16x8*)
                    &A_l[(jj * 64 + w * 16 + (lane & 15)) * SG_LDA + mk * 32 + ((lane >> 4) * 8)];
#pragma unroll
                for (int ns = 0; ns < 4; ++ns) {
                    const bf16x8 bv = *(const bf16x8*)
                        &U_l[(jj * 64 + ns * 16 + (lane & 15)) * SG_LDA + mk * 32 + ((lane >> 4) * 8)];
                    acc[ns] = __builtin_amdgcn_mfma_f32_16x16x32_bf16(av, bv, acc[ns], 0, 0, 0);
                }
            }
        }
        __syncthreads();
    }
#pragma unroll
    for (int ns = 0; ns < 4; ++ns) {
        const int n = ns * 16 + (lane & 15);
        const int bb = bp * 2 + (n >> 5), kkk = n & 31;
        float* dst = Sbuf + ((size_t)bb * NTB + kkk) * NS + i0 + w * 16 + ((lane >> 4) * 4);
        *(floatx4*)dst = acc[ns];
    }
}

// ---------------------------------------------------------------------------
// Fused: blocks 0..31 = block-carry scan (per batch); block 32 = impulse
// response h (independent; runs concurrently instead of a serial launch).
// ---------------------------------------------------------------------------
__global__ void __launch_bounds__(256) scan_himp_kernel(const float* __restrict__ Sbuf,
                                                        float* __restrict__ Rbuf,
                                                        const float* __restrict__ a,
                                                        float* __restrict__ hbuf) {
    __shared__ __align__(16) char smem[69632];
    const int tid = threadIdx.x;
    if (blockIdx.x < NB) {
        // ---------------- scan ----------------
        float* S_l = (float*)smem;                 // 64 KB
        float* Rc  = (float*)(smem + 65536);       // 2 * 512 * 4
        const int b = blockIdx.x;
        const float4* src = (const float4*)(Sbuf + (size_t)b * NTB * NS);
        for (int k = tid; k < NTB * NS / 4; k += 256) ((float4*)S_l)[k] = src[k];
        if (tid < 128) ((float4*)Rc)[tid] = make_float4(0.f, 0.f, 0.f, 0.f);
        __syncthreads();
        int cur = 0;
        for (int k = 0; k < NTB; ++k) {
            if (tid < 128) {
                const int i0 = tid * 4;
                float4 r = *(const float4*)&Rc[cur * NS + i0];
                *(float4*)(Rbuf + ((size_t)b * NTB + k) * NS + i0) = r;
                float4 s = *(const float4*)&S_l[k * NS + i0];
                float4 rp = (i0 >= TB) ? *(const float4*)&Rc[cur * NS + i0 - TB]
                                       : make_float4(0.f, 0.f, 0.f, 0.f);
                float4 nv = make_float4(s.x + rp.x, s.y + rp.y, s.z + rp.z, s.w + rp.w);
                *(float4*)&Rc[(cur ^ 1) * NS + i0] = nv;
            }
            __syncthreads();
            cur ^= 1;
        }
    } else {
        // ---------------- himp (256-thread version) ----------------
        float* a_l   = (float*)smem;               // 512
        float* h_l   = (float*)(smem + 2048);      // 2048
        float* part  = (float*)(smem + 2048 + 8192);   // 4*128
        float* rhs_l = (float*)(smem + 2048 + 8192 + 2048); // 128
        for (int i = tid; i < NS; i += 256) a_l[i] = a[i];
        __syncthreads();
        // bootstrap h[0:64] (wave 0, serial)
        if (tid < 64) {
            if (tid == 0) h_l[0] = 1.f;
            for (int t = 1; t < 64; ++t) {
                float pr = (tid < t) ? a_l[tid] * h_l[t - 1 - tid] : 0.f;
#pragma unroll
                for (int off = 32; off; off >>= 1) pr += __shfl_xor(pr, off);
                if (tid == 0) h_l[t] = -pr;
            }
        }
        __syncthreads();
        // extend 64 -> 128 (one doubling step)
        {
            const int k = tid & 63, grp = tid >> 6;
            float acc = 0.f;
#pragma unroll
            for (int jj = 0; jj < 16; ++jj) {
                const int j = k + 1 + grp * 16 + jj;
                acc += a_l[j - 1] * h_l[64 + k - j];
            }
            part[grp * 128 + k] = acc;
            __syncthreads();
            if (tid < 64) {
                rhs_l[tid] = -(part[tid] + part[128 + tid] + part[256 + tid] + part[384 + tid]);
            }
            __syncthreads();
            if (tid < 64) {
                float sv = 0.f;
                for (int j = 0; j <= tid; ++j) sv += h_l[j] * rhs_l[tid - j];
                h_l[64 + tid] = sv;
            }
            __syncthreads();
        }
        // blocks of 128: t0 = 128..2048
        for (int t0 = 128; t0 < SEQ; t0 += 128) {
            const int k = tid & 127, half = tid >> 7;
            const int dmax = min(NS - k, t0);
            const int dLo = 1 + half * 256;
            const int dHi = min(dmax, (half + 1) * 256);
            float acc = 0.f;
            for (int d = dLo; d <= dHi; ++d) acc += a_l[k + d - 1] * h_l[t0 - d];
            part[half * 128 + k] = acc;
            __syncthreads();
            if (tid < 128) rhs_l[tid] = -(part[tid] + part[128 + tid]);
            __syncthreads();
            if (tid < 128) {
                float sv = 0.f;
                for (int j = 0; j <= tid; ++j) sv += h_l[j] * rhs_l[tid - j];
                h_l[t0 + tid] = sv;
            }
            __syncthreads();
        }
        for (int i = tid; i < SEQ; i += 256) hbuf[i] = h_l[i];
    }
}

// ---------------------------------------------------------------------------
// ytile (MFMA, direct global A-frags): per (t-block, batch): Bu chunks,
// uniform-t diagonal cumsum, y = C*G + D*u, emit f.  3 barriers/chunk.
// ---------------------------------------------------------------------------
__global__ void __launch_bounds__(256) ytile_kernel(
    const unsigned short* __restrict__ ubf, const unsigned short* __restrict__ Bws,
    const unsigned short* __restrict__ Cws, const unsigned short* __restrict__ Dws,
    const float* __restrict__ Rbuf, float* __restrict__ fbuf, float* __restrict__ y) {
    __shared__ unsigned short u_b[TB * LDU];   // 9.2 KB
    __shared__ float bu[TB * LDBU];            // 17.4 KB
    __shared__ float colBuf[2][TB];

    const int blk = blockIdx.x, b = blockIdx.y;
    const int t0 = blk * TB;
    const int tid = threadIdx.x;
    const int lane = tid & 63, w = tid >> 6;
    const int row16 = lane & 15, quad = lane >> 4;

    // stage u tile (bf16, pre-converted)
#pragma unroll
    for (int r = 0; r < 2; ++r) {
        const int id = tid + r * 256;
        const int t = id >> 3, q8 = (id & 7) * 8;
        *(uint4*)&u_b[t * LDU + q8] =
            *(const uint4*)(ubf + ((size_t)b * SEQ + t0 + t) * MI + q8);
    }
    if (tid < TB) colBuf[0][tid] = 0.f;

    floatx4 accY[4];
#pragma unroll
    for (int nt = 0; nt < 4; ++nt) accY[nt] = (floatx4){0.f, 0.f, 0.f, 0.f};
    __syncthreads();

    // preload u B-operand frags once (u_b read-only hereafter)
    bf16x8 ufr0[4], ufr1[4];
#pragma unroll
    for (int nt = 0; nt < 4; ++nt) {
        const int t = nt * 16 + row16;
        ufr0[nt] = *(const bf16x8*)&u_b[t * LDU + quad * 8];
        ufr1[nt] = *(const bf16x8*)&u_b[t * LDU + 32 + quad * 8];
    }

    int cur = 0;
    for (int ch = 0; ch < NCH; ++ch) {
        // direct global A-frags (B rows / C rows; L1/L2-hot broadcast data)
        const bf16x8 bf0 = *(const bf16x8*)(Bws + (size_t)(ch * CH + w * 16 + row16) * MI + quad * 8);
        const bf16x8 bf1 = *(const bf16x8*)(Bws + (size_t)(ch * CH + w * 16 + row16) * MI + 32 + quad * 8);
        const bf16x8 cf0 = *(const bf16x8*)(Cws + (size_t)(w * 16 + row16) * NS + ch * CH + quad * 8);
        const bf16x8 cf1 = *(const bf16x8*)(Cws + (size_t)(w * 16 + row16) * NS + ch * CH + 32 + quad * 8);

        // phase A: Bu chunk -> bu
#pragma unroll
        for (int nt = 0; nt < 4; ++nt) {
            floatx4 d = {0.f, 0.f, 0.f, 0.f};
            d = __builtin_amdgcn_mfma_f32_16x16x32_bf16(bf0, ufr0[nt], d, 0, 0, 0);
            d = __builtin_amdgcn_mfma_f32_16x16x32_bf16(bf1, ufr1[nt], d, 0, 0, 0);
            const int t = nt * 16 + row16;
            *(floatx4*)&bu[t * LDBU + w * 16 + quad * 4] = d;
        }
        __syncthreads();

        // diagonal walk — uniform t across lanes (conflict-free)
        const int nxt = cur ^ 1;
        if (tid < 127) {
            const int cl = tid - 63;
            float carry;
            if (cl < 0) carry = colBuf[cur][-cl - 1];
            else {
                const int gi = ch * CH + cl;
                carry = (gi >= 1) ? Rbuf[((size_t)b * NTB + blk) * NS + gi - 1] : 0.f;
            }
            for (int t = 0; t < TB; ++t) {
                const int il = cl + t;
                if (il >= 0 && il < CH) {
                    carry += bu[t * LDBU + il];
                    bu[t * LDBU + il] = carry;
                    if (il == CH - 1) {
                        if (ch == NCH - 1) fbuf[(size_t)b * SEQ + t0 + t] = carry;
                        else if (t < TB - 1) colBuf[nxt][t] = carry;
                    }
                }
            }
        }
        __syncthreads();

        // phase B: accY += C[:,chunk] * G[chunk]
#pragma unroll
        for (int nt = 0; nt < 4; ++nt) {
            const int t  = nt * 16 + row16;
            const int k0 = quad * 8;
            floatx4 g0 = *(const floatx4*)&bu[t * LDBU + k0];
            floatx4 g1 = *(const floatx4*)&bu[t * LDBU + k0 + 4];
            floatx4 h0 = *(const floatx4*)&bu[t * LDBU + 32 + k0];
            floatx4 h1 = *(const floatx4*)&bu[t * LDBU + 32 + k0 + 4];
            accY[nt] = __builtin_amdgcn_mfma_f32_16x16x32_bf16(cf0, cvt8(g0, g1), accY[nt], 0, 0, 0);
            accY[nt] = __builtin_amdgcn_mfma_f32_16x16x32_bf16(cf1, cvt8(h0, h1), accY[nt], 0, 0, 0);
        }
        __syncthreads();
        cur = nxt;
    }

    // epilogue: += D*u (direct global D frags), store y
    const bf16x8 df0 = *(const bf16x8*)(Dws + (size_t)(w * 16 + row16) * MI + quad * 8);
    const bf16x8 df1 = *(const bf16x8*)(Dws + (size_t)(w * 16 + row16) * MI + 32 + quad * 8);
#pragma unroll
    for (int nt = 0; nt < 4; ++nt) {
        const int t = nt * 16 + row16;
        accY[nt] = __builtin_amdgcn_mfma_f32_16x16x32_bf16(df0, ufr0[nt], accY[nt], 0, 0, 0);
        accY[nt] = __builtin_amdgcn_mfma_f32_16x16x32_bf16(df1, ufr1[nt], accY[nt], 0, 0, 0);
        const int p0 = w * 16 + quad * 4;
        *(floatx4*)(y + ((size_t)b * SEQ + t0 + t) * PO + p0) = accY[nt];
    }
}

// ---------------------------------------------------------------------------
// s[b][t] = sum_{j=0..t} h[j] f[b][t-j]
// ---------------------------------------------------------------------------
__global__ void __launch_bounds__(256) sconv_kernel(const float* __restrict__ fbuf,
                                                    const float* __restrict__ hbuf,
                                                    float* __restrict__ sbuf) {
    __shared__ float f_l[SEQ];
    __shared__ float h_lc[SEQ + 8];
    __shared__ float part[4][TB];
    const int blk = blockIdx.x, b = blockIdx.y, tid = threadIdx.x;
    const int t0 = blk * TB;
    const int len = t0 + TB;
    {
        const float4* fs = (const float4*)(fbuf + (size_t)b * SEQ);
        const float4* hs = (const float4*)hbuf;
        for (int i = tid; i < len / 4; i += 256) {
            ((float4*)f_l)[i] = fs[i];
            ((float4*)h_lc)[i] = hs[i];
        }
    }
    __syncthreads();
    const int dt = tid & 63, grp = tid >> 6;
    const int t = t0 + dt;
    float acc = 0.f;
    for (int j4 = grp * 4; j4 <= t; j4 += 16) {
        const float4 hv = *(const float4*)&h_lc[j4];
        if (j4 + 0 <= t) acc += hv.x * f_l[t - j4 - 0];
        if (j4 + 1 <= t) acc += hv.y * f_l[t - j4 - 1];
        if (j4 + 2 <= t) acc += hv.z * f_l[t - j4 - 2];
        if (j4 + 3 <= t) acc += hv.w * f_l[t - j4 - 3];
    }
    part[grp][dt] = acc;
    __syncthreads();
    if (tid < TB) {
        sbuf[(size_t)b * SEQ + t0 + tid] =
            part[0][tid] + part[1][tid] + part[2][tid] + part[3][tid];
    }
}

// ---------------------------------------------------------------------------
// corr (MFMA, direct global q-frags, double-buffered Sw, 1 barrier/chunk):
// y[b,t,p] -= sum_j qT[p][j] * s[b, t-1-j]
// ---------------------------------------------------------------------------
__global__ void __launch_bounds__(256) corr_kernel(
    const float* __restrict__ sbuf, const unsigned short* __restrict__ qT,
    float* __restrict__ y) {
    __shared__ float s_l[NS + TB];
    __shared__ unsigned short Sw[2][TB * LDU];
    const int blk = blockIdx.x, b = blockIdx.y, tid = threadIdx.x;
    const int t0 = blk * TB;
    const int lane = tid & 63, w = tid >> 6;
    const int row16 = lane & 15, quad = lane >> 4;
    for (int idx = tid; idx < NS + TB; idx += 256) {
        const int t = t0 - NS + idx;
        s_l[idx] = (t >= 0) ? sbuf[(size_t)b * SEQ + t] : 0.f;
    }
    floatx4 acc[4];
#pragma unroll
    for (int nt = 0; nt < 4; ++nt) acc[nt] = (floatx4){0.f, 0.f, 0.f, 0.f};
    __syncthreads();

    for (int ch = 0; ch < NCH; ++ch) {
        const int buf = ch & 1;
        const bf16x8 qf0 = *(const bf16x8*)(qT + (size_t)(w * 16 + row16) * NS + ch * CH + quad * 8);
        const bf16x8 qf1 = *(const bf16x8*)(qT + (size_t)(w * 16 + row16) * NS + ch * CH + 32 + quad * 8);
        {
            const int r = tid >> 2, c0 = (tid & 3) * 16;
            unsigned short tmp[16];
            const int base = 511 + r - ch * CH - c0;
#pragma unroll
            for (int jj = 0; jj < 16; ++jj) tmp[jj] = f2bf(s_l[base - jj]);
            *(uint4*)&Sw[buf][r * LDU + c0]     = *(uint4*)&tmp[0];
            *(uint4*)&Sw[buf][r * LDU + c0 + 8] = *(uint4*)&tmp[8];
        }
        __syncthreads();
#pragma unroll
        for (int nt = 0; nt < 4; ++nt) {
            const int t = nt * 16 + row16;
            bf16x8 s0 = *(const bf16x8*)&Sw[buf][t * LDU + quad * 8];
            bf16x8 s1 = *(const bf16x8*)&Sw[buf][t * LDU + 32 + quad * 8];
            acc[nt] = __builtin_amdgcn_mfma_f32_16x16x32_bf16(qf0, s0, acc[nt], 0, 0, 0);
            acc[nt] = __builtin_amdgcn_mfma_f32_16x16x32_bf16(qf1, s1, acc[nt], 0, 0, 0);
        }
        // no trailing barrier: next chunk writes the other Sw buffer, and the
        // lgkmcnt wait before these MFMAs completed our reads pre-barrier.
    }
#pragma unroll
    for (int nt = 0; nt < 4; ++nt) {
        const int t = nt * 16 + row16;
        const int p0 = w * 16 + quad * 4;
        float* yp = y + ((size_t)b * SEQ + t0 + t) * PO + p0;
        floatx4 old = *(const floatx4*)yp;
        *(floatx4*)yp = old - acc[nt];
    }
}

// ---------------------------------------------------------------------------
extern "C" void kernel_launch(void* const* d_in, const int* in_sizes, int n_in,
                              void* d_out, int out_size, void* d_ws,
                              size_t ws_size, hipStream_t stream) {
    const float* u  = (const float*)d_in[0];
    const float* a  = (const float*)d_in[1];
    const float* B  = (const float*)d_in[2];
    const float* Cm = (const float*)d_in[3];
    const float* Dm = (const float*)d_in[4];
    float* y = (float*)d_out;

    char* ws = (char*)d_ws;
    unsigned short* Bws = (unsigned short*)ws;                  ws += NS * MI * 2;
    unsigned short* Cws = (unsigned short*)ws;                  ws += PO * NS * 2;
    unsigned short* Dws = (unsigned short*)ws;                  ws += PO * MI * 2;
    unsigned short* qTw = (unsigned short*)ws;                  ws += PO * NS * 2;
    unsigned short* ubf = (unsigned short*)ws;                  ws += (size_t)NB * SEQ * MI * 2;
    unsigned short* Bft = (unsigned short*)ws;                  ws += (size_t)NS * 4096 * 2;
    float* Sbuf = (float*)ws;                                   ws += (size_t)NB * NTB * NS * 4;
    float* Rbuf = (float*)ws;                                   ws += (size_t)NB * NTB * NS * 4;
    float* fbuf = (float*)ws;                                   ws += (size_t)NB * SEQ * 4;
    float* sbuf = (float*)ws;                                   ws += (size_t)NB * SEQ * 4;
    float* hbuf = (float*)ws;                                   // 2048 floats (~17.5 MB total)

    prep_all_kernel<<<dim3(2896), dim3(256), 0, stream>>>(
        u, B, Cm, Dm, a, ubf, Bft, Bws, Cws, Dws, qTw);
    sgemm_kernel<<<dim3(8, 16), dim3(256), 0, stream>>>(ubf, Bft, Sbuf);
    scan_himp_kernel<<<dim3(NB + 1), dim3(256), 0, stream>>>(Sbuf, Rbuf, a, hbuf);
    ytile_kernel<<<dim3(NTB, NB), dim3(256), 0, stream>>>(
        ubf, Bws, Cws, Dws, Rbuf, fbuf, y);
    sconv_kernel<<<dim3(NTB, NB), dim3(256), 0, stream>>>(fbuf, hbuf, sbuf);
    corr_kernel<<<dim3(NTB, NB), dim3(256), 0, stream>>>(sbuf, qTw, y);
}

// Round 6
// 286.044 us; speedup vs baseline: 1.7978x; 1.4283x over previous
//
#include <hip/hip_runtime.h>

// Problem constants
#define SEQ  2048
#define NB   32
#define NS   512
#define MI   64   // M_IN
#define PO   64   // P_OUT
#define TB   64   // t-block
#define NTB  32   // SEQ/TB
#define CH   64   // i-chunk
#define NCH  8    // NS/CH
#define LDU  72   // u_b / Sw stride (ushort)
#define LDBU 68   // bu stride (float)
#define SG_LDA 72 // sgemm LDS stride (ushort)

typedef __attribute__((ext_vector_type(8))) __bf16 bf16x8;
typedef __attribute__((ext_vector_type(4))) float  floatx4;

__device__ inline unsigned short f2bf(float f) {
    unsigned u = __builtin_bit_cast(unsigned, f);
    u += 0x7fff + ((u >> 16) & 1);           // RNE
    return (unsigned short)(u >> 16);
}

__device__ inline bf16x8 cvt8(floatx4 lo, floatx4 hi) {
    bf16x8 r;
    r[0] = (__bf16)lo[0]; r[1] = (__bf16)lo[1]; r[2] = (__bf16)lo[2]; r[3] = (__bf16)lo[3];
    r[4] = (__bf16)hi[0]; r[5] = (__bf16)hi[1]; r[6] = (__bf16)hi[2]; r[7] = (__bf16)hi[3];
    return r;
}

// ---------------------------------------------------------------------------
// Fused prep: [0,2048) u->bf16 | [2048,2560) BflatT | [2560,2624) q
// | [2624,2896) B/C/D -> bf16
// ---------------------------------------------------------------------------
__global__ void __launch_bounds__(256) prep_all_kernel(
    const float* __restrict__ u, const float* __restrict__ B,
    const float* __restrict__ C, const float* __restrict__ D,
    const float* __restrict__ a,
    unsigned short* __restrict__ ubf, unsigned short* __restrict__ BflatT,
    unsigned short* __restrict__ Bws, unsigned short* __restrict__ Cws,
    unsigned short* __restrict__ Dws, unsigned short* __restrict__ qT) {
    __shared__ float a_ext[1024];
    const int bx = blockIdx.x, tid = threadIdx.x;
    if (bx < 2048) {                       // ---- uconv
        const size_t base = ((size_t)bx * 256 + tid) * 8;
        float4 f0 = *(const float4*)(u + base);
        float4 f1 = *(const float4*)(u + base + 4);
        unsigned short tmp[8];
        tmp[0] = f2bf(f0.x); tmp[1] = f2bf(f0.y); tmp[2] = f2bf(f0.z); tmp[3] = f2bf(f0.w);
        tmp[4] = f2bf(f1.x); tmp[5] = f2bf(f1.y); tmp[6] = f2bf(f1.z); tmp[7] = f2bf(f1.w);
        *(uint4*)(ubf + base) = *(uint4*)&tmp[0];
    } else if (bx < 2560) {                // ---- BflatT[i][(j,m)] = B[i-j,m]
        const int i = bx - 2048;
        for (int r = 0; r < 2; ++r) {
            const int id = tid + r * 256;
            const int j = id >> 3, q8 = (id & 7) * 8;
            unsigned short tmp[8];
            if (i >= j) {
                const float4 f0 = *(const float4*)(B + (size_t)(i - j) * MI + q8);
                const float4 f1 = *(const float4*)(B + (size_t)(i - j) * MI + q8 + 4);
                tmp[0] = f2bf(f0.x); tmp[1] = f2bf(f0.y); tmp[2] = f2bf(f0.z); tmp[3] = f2bf(f0.w);
                tmp[4] = f2bf(f1.x); tmp[5] = f2bf(f1.y); tmp[6] = f2bf(f1.z); tmp[7] = f2bf(f1.w);
            } else {
#pragma unroll
                for (int z = 0; z < 8; ++z) tmp[z] = 0;
            }
            *(uint4*)(BflatT + (size_t)i * 4096 + j * 64 + q8) = *(uint4*)&tmp[0];
        }
    } else if (bx < 2624) {                // ---- q: qT[p][j]
        const int p = bx - 2560;
        for (int x = tid; x < 1024; x += 256) a_ext[x] = (x < NS) ? a[x] : 0.f;
        __syncthreads();
        const int j0 = tid, j1 = tid + 256;
        float acc0 = 0.f, acc1 = 0.f;
        const float4* crow = (const float4*)(C + (size_t)p * NS);
        for (int i4 = 0; i4 < NS / 4; ++i4) {
            const float4 cv = crow[i4];
            const int base = 511 - i4 * 4;
            acc0 += cv.x * a_ext[base + j0]     + cv.y * a_ext[base - 1 + j0] +
                    cv.z * a_ext[base - 2 + j0] + cv.w * a_ext[base - 3 + j0];
            acc1 += cv.x * a_ext[base + j1]     + cv.y * a_ext[base - 1 + j1] +
                    cv.z * a_ext[base - 2 + j1] + cv.w * a_ext[base - 3 + j1];
        }
        qT[(size_t)p * NS + j0] = f2bf(acc0);
        qT[(size_t)p * NS + j1] = f2bf(acc1);
    } else {                               // ---- B/C/D bf16 cvt
        const int idx = (bx - 2624) * 256 + tid;
        const int nB = NS * MI, nC = PO * NS, nD = PO * MI;
        if (idx < nB) Bws[idx] = f2bf(B[idx]);
        else if (idx < nB + nC) Cws[idx - nB] = f2bf(C[idx - nB]);
        else if (idx < nB + nC + nD) Dws[idx - nB - nC] = f2bf(D[idx - nB - nC]);
    }
}

// ---------------------------------------------------------------------------
// S-GEMM: S[(b,k), i] = sum_{(j,m)} BflatT[i][(j,m)] * u[b, k*64+63-j, m]
// ---------------------------------------------------------------------------
__global__ void __launch_bounds__(256) sgemm_kernel(const unsigned short* __restrict__ ubf,
                                                    const unsigned short* __restrict__ BflatT,
                                                    float* __restrict__ Sbuf) {
    __shared__ unsigned short A_l[4 * 64 * SG_LDA];
    __shared__ unsigned short U_l[4 * 64 * SG_LDA];
    const int ib = blockIdx.x, bp = blockIdx.y;
    const int tid = threadIdx.x, lane = tid & 63, w = tid >> 6;
    const int i0 = ib * 64;
    floatx4 acc[4];
#pragma unroll
    for (int ns = 0; ns < 4; ++ns) acc[ns] = (floatx4){0.f, 0.f, 0.f, 0.f};

    for (int jg = 0; jg < 16; ++jg) {
#pragma unroll
        for (int r = 0; r < 8; ++r) {
            const int id = tid + r * 256;
            const int row = id >> 5;
            const int jj = (id >> 3) & 3, q8 = (id & 7) * 8;
            const int j = jg * 4 + jj;
            *(uint4*)&A_l[(jj * 64 + row) * SG_LDA + q8] =
                *(const uint4*)(BflatT + (size_t)(i0 + row) * 4096 + j * 64 + q8);
            const int bb = bp * 2 + (row >> 5), kkk = row & 31;
            *(uint4*)&U_l[(jj * 64 + row) * SG_LDA + q8] =
                *(const uint4*)(ubf + ((size_t)bb * SEQ + kkk * 64 + 63 - j) * MI + q8);
        }
        __syncthreads();
#pragma unroll
        for (int jj = 0; jj < 4; ++jj) {
#pragma unroll
            for (int mk = 0; mk < 2; ++mk) {
                const bf16x8 av = *(const bf16x8*)
                    &A_l[(jj * 64 + w * 16 + (lane & 15)) * SG_LDA + mk * 32 + ((lane >> 4) * 8)];
#pragma unroll
                for (int ns = 0; ns < 4; ++ns) {
                    const bf16x8 bv = *(const bf16x8*)
                        &U_l[(jj * 64 + ns * 16 + (lane & 15)) * SG_LDA + mk * 32 + ((lane >> 4) * 8)];
                    acc[ns] = __builtin_amdgcn_mfma_f32_16x16x32_bf16(av, bv, acc[ns], 0, 0, 0);
                }
            }
        }
        __syncthreads();
    }
#pragma unroll
    for (int ns = 0; ns < 4; ++ns) {
        const int n = ns * 16 + (lane & 15);
        const int bb = bp * 2 + (n >> 5), kkk = n & 31;
        float* dst = Sbuf + ((size_t)bb * NTB + kkk) * NS + i0 + w * 16 + ((lane >> 4) * 4);
        *(floatx4*)dst = acc[ns];
    }
}

// ---------------------------------------------------------------------------
// Fused (1024 threads): blocks 0..31 = block-carry scan (per batch);
// block 32 = impulse response h. himp is fully unrolled: fixed trip counts,
// register-cached taps, zero-padded h_ext / rhs_ext (no per-lane bounds).
// ---------------------------------------------------------------------------
__global__ void __launch_bounds__(1024) scan_himp_kernel(const float* __restrict__ Sbuf,
                                                         float* __restrict__ Rbuf,
                                                         const float* __restrict__ a,
                                                         float* __restrict__ hbuf) {
    __shared__ __align__(16) char smem[69632];
    const int tid = threadIdx.x;
    if (blockIdx.x < NB) {
        // ---------------- scan ----------------
        float* S_l = (float*)smem;                 // 64 KB
        float* Rc  = (float*)(smem + 65536);       // 2 * 512 * 4
        const int b = blockIdx.x;
        const float4* src = (const float4*)(Sbuf + (size_t)b * NTB * NS);
        for (int k = tid; k < NTB * NS / 4; k += 1024) ((float4*)S_l)[k] = src[k];
        if (tid < 128) ((float4*)Rc)[tid] = make_float4(0.f, 0.f, 0.f, 0.f);
        __syncthreads();
        int cur = 0;
        for (int k = 0; k < NTB; ++k) {
            if (tid < 128) {
                const int i0 = tid * 4;
                float4 r = *(const float4*)&Rc[cur * NS + i0];
                *(float4*)(Rbuf + ((size_t)b * NTB + k) * NS + i0) = r;
                float4 s = *(const float4*)&S_l[k * NS + i0];
                float4 rp = (i0 >= TB) ? *(const float4*)&Rc[cur * NS + i0 - TB]
                                       : make_float4(0.f, 0.f, 0.f, 0.f);
                float4 nv = make_float4(s.x + rp.x, s.y + rp.y, s.z + rp.z, s.w + rp.w);
                *(float4*)&Rc[(cur ^ 1) * NS + i0] = nv;
            }
            __syncthreads();
            cur ^= 1;
        }
    } else {
        // ---------------- himp ----------------
        // layout: a_l [0,2560) | h_ext [2560,12800) | part [12800,20992)
        //         rhs_ext [20992,22016)
        float* a_l     = (float*)smem;                  // 640 floats (zero-pad)
        float* h_ext   = (float*)(smem + 2560);         // 512 zeros + h[0:2048]
        float* part    = (float*)(smem + 12800);        // 16 * 128
        float* rhs_ext = (float*)(smem + 20992);        // 128 zeros + 128
        const int kk = tid & 63, grp = tid >> 6;        // 16 groups of 64

        for (int x = tid; x < 640; x += 1024) a_l[x] = (x < NS) ? a[x] : 0.f;
        for (int x = tid; x < 512; x += 1024) h_ext[x] = 0.f;   // pad below
        if (tid < 128) rhs_ext[tid] = 0.f;                       // pad below
        __syncthreads();

        // register-cache taps: k = kk (+64), d in [grp*32+1, grp*32+32]
        float a0r[32], a1r[32];
#pragma unroll
        for (int i = 0; i < 32; ++i) a0r[i] = a_l[kk + grp * 32 + i];
#pragma unroll
        for (int i = 0; i < 32; ++i) a1r[i] = a_l[kk + 64 + grp * 32 + i];

        // bootstrap h[0:64] serially (wave 0; same-wave LDS ordering)
        if (tid < 64) {
            if (tid == 0) h_ext[512] = 1.f;
            for (int t = 1; t < 64; ++t) {
                float pr = (tid < t) ? a_l[tid] * h_ext[512 + t - 1 - tid] : 0.f;
#pragma unroll
                for (int off = 32; off; off >>= 1) pr += __shfl_xor(pr, off);
                if (tid == 0) h_ext[512 + t] = -pr;
            }
        }
        __syncthreads();

        // doubling 64 -> 128: blocked step at t0=64, width 64
        {
            const int t0 = 64;
            float acc0 = 0.f;
#pragma unroll
            for (int m = 0; m < 8; ++m) {
                const float4 hv = *(const float4*)&h_ext[512 + t0 - grp * 32 - 4 - 4 * m];
                acc0 += a0r[4 * m + 0] * hv.w + a0r[4 * m + 1] * hv.z +
                        a0r[4 * m + 2] * hv.y + a0r[4 * m + 3] * hv.x;
            }
            part[grp * 128 + kk] = acc0;
            __syncthreads();
            if (tid < 64) {
                float r = 0.f;
#pragma unroll
                for (int g = 0; g < 16; ++g) r += part[g * 128 + tid];
                rhs_ext[128 + tid] = -r;
            }
            __syncthreads();
            if (tid < 64) {
                float s0 = 0.f, s1 = 0.f, s2 = 0.f, s3 = 0.f;
#pragma unroll
                for (int j = 0; j < 64; j += 4) {
                    const float4 h4 = *(const float4*)&h_ext[512 + j];
                    s0 += h4.x * rhs_ext[128 + tid - j];
                    s1 += h4.y * rhs_ext[128 + tid - j - 1];
                    s2 += h4.z * rhs_ext[128 + tid - j - 2];
                    s3 += h4.w * rhs_ext[128 + tid - j - 3];
                }
                h_ext[512 + t0 + tid] = s0 + s1 + s2 + s3;
            }
            __syncthreads();
        }

        // main blocks of 128: t0 = 128..1920
        for (int t0 = 128; t0 < SEQ; t0 += 128) {
            float acc0 = 0.f, acc1 = 0.f;
#pragma unroll
            for (int m = 0; m < 8; ++m) {
                const float4 hv = *(const float4*)&h_ext[512 + t0 - grp * 32 - 4 - 4 * m];
                acc0 += a0r[4 * m + 0] * hv.w + a0r[4 * m + 1] * hv.z +
                        a0r[4 * m + 2] * hv.y + a0r[4 * m + 3] * hv.x;
                acc1 += a1r[4 * m + 0] * hv.w + a1r[4 * m + 1] * hv.z +
                        a1r[4 * m + 2] * hv.y + a1r[4 * m + 3] * hv.x;
            }
            part[grp * 128 + kk]      = acc0;
            part[grp * 128 + kk + 64] = acc1;
            __syncthreads();
            if (tid < 128) {
                float r = 0.f;
#pragma unroll
                for (int g = 0; g < 16; ++g) r += part[g * 128 + tid];
                rhs_ext[128 + tid] = -r;
            }
            __syncthreads();
            if (tid < 128) {
                float s0 = 0.f, s1 = 0.f, s2 = 0.f, s3 = 0.f;
#pragma unroll
                for (int j = 0; j < 128; j += 4) {
                    const float4 h4 = *(const float4*)&h_ext[512 + j];
                    s0 += h4.x * rhs_ext[128 + tid - j];
                    s1 += h4.y * rhs_ext[128 + tid - j - 1];
                    s2 += h4.z * rhs_ext[128 + tid - j - 2];
                    s3 += h4.w * rhs_ext[128 + tid - j - 3];
                }
                h_ext[512 + t0 + tid] = s0 + s1 + s2 + s3;
            }
            __syncthreads();
        }
        for (int i = tid; i < SEQ; i += 1024) hbuf[i] = h_ext[512 + i];
    }
}

// ---------------------------------------------------------------------------
// ytile (MFMA, direct global A-frags): per (t-block, batch): Bu chunks,
// uniform-t diagonal cumsum, y = C*G + D*u, emit f.  3 barriers/chunk.
// ---------------------------------------------------------------------------
__global__ void __launch_bounds__(256) ytile_kernel(
    const unsigned short* __restrict__ ubf, const unsigned short* __restrict__ Bws,
    const unsigned short* __restrict__ Cws, const unsigned short* __restrict__ Dws,
    const float* __restrict__ Rbuf, float* __restrict__ fbuf, float* __restrict__ y) {
    __shared__ unsigned short u_b[TB * LDU];   // 9.2 KB
    __shared__ float bu[TB * LDBU];            // 17.4 KB
    __shared__ float colBuf[2][TB];

    const int blk = blockIdx.x, b = blockIdx.y;
    const int t0 = blk * TB;
    const int tid = threadIdx.x;
    const int lane = tid & 63, w = tid >> 6;
    const int row16 = lane & 15, quad = lane >> 4;

    // stage u tile (bf16, pre-converted)
#pragma unroll
    for (int r = 0; r < 2; ++r) {
        const int id = tid + r * 256;
        const int t = id >> 3, q8 = (id & 7) * 8;
        *(uint4*)&u_b[t * LDU + q8] =
            *(const uint4*)(ubf + ((size_t)b * SEQ + t0 + t) * MI + q8);
    }
    if (tid < TB) colBuf[0][tid] = 0.f;

    floatx4 accY[4];
#pragma unroll
    for (int nt = 0; nt < 4; ++nt) accY[nt] = (floatx4){0.f, 0.f, 0.f, 0.f};
    __syncthreads();

    // preload u B-operand frags once (u_b read-only hereafter)
    bf16x8 ufr0[4], ufr1[4];
#pragma unroll
    for (int nt = 0; nt < 4; ++nt) {
        const int t = nt * 16 + row16;
        ufr0[nt] = *(const bf16x8*)&u_b[t * LDU + quad * 8];
        ufr1[nt] = *(const bf16x8*)&u_b[t * LDU + 32 + quad * 8];
    }

    int cur = 0;
    for (int ch = 0; ch < NCH; ++ch) {
        // direct global A-frags (B rows / C rows; L1/L2-hot broadcast data)
        const bf16x8 bf0 = *(const bf16x8*)(Bws + (size_t)(ch * CH + w * 16 + row16) * MI + quad * 8);
        const bf16x8 bf1 = *(const bf16x8*)(Bws + (size_t)(ch * CH + w * 16 + row16) * MI + 32 + quad * 8);
        const bf16x8 cf0 = *(const bf16x8*)(Cws + (size_t)(w * 16 + row16) * NS + ch * CH + quad * 8);
        const bf16x8 cf1 = *(const bf16x8*)(Cws + (size_t)(w * 16 + row16) * NS + ch * CH + 32 + quad * 8);

        // phase A: Bu chunk -> bu
#pragma unroll
        for (int nt = 0; nt < 4; ++nt) {
            floatx4 d = {0.f, 0.f, 0.f, 0.f};
            d = __builtin_amdgcn_mfma_f32_16x16x32_bf16(bf0, ufr0[nt], d, 0, 0, 0);
            d = __builtin_amdgcn_mfma_f32_16x16x32_bf16(bf1, ufr1[nt], d, 0, 0, 0);
            const int t = nt * 16 + row16;
            *(floatx4*)&bu[t * LDBU + w * 16 + quad * 4] = d;
        }
        __syncthreads();

        // diagonal walk — uniform t across lanes (conflict-free)
        const int nxt = cur ^ 1;
        if (tid < 127) {
            const int cl = tid - 63;
            float carry;
            if (cl < 0) carry = colBuf[cur][-cl - 1];
            else {
                const int gi = ch * CH + cl;
                carry = (gi >= 1) ? Rbuf[((size_t)b * NTB + blk) * NS + gi - 1] : 0.f;
            }
            for (int t = 0; t < TB; ++t) {
                const int il = cl + t;
                if (il >= 0 && il < CH) {
                    carry += bu[t * LDBU + il];
                    bu[t * LDBU + il] = carry;
                    if (il == CH - 1) {
                        if (ch == NCH - 1) fbuf[(size_t)b * SEQ + t0 + t] = carry;
                        else if (t < TB - 1) colBuf[nxt][t] = carry;
                    }
                }
            }
        }
        __syncthreads();

        // phase B: accY += C[:,chunk] * G[chunk]
#pragma unroll
        for (int nt = 0; nt < 4; ++nt) {
            const int t  = nt * 16 + row16;
            const int k0 = quad * 8;
            floatx4 g0 = *(const floatx4*)&bu[t * LDBU + k0];
            floatx4 g1 = *(const floatx4*)&bu[t * LDBU + k0 + 4];
            floatx4 h0 = *(const floatx4*)&bu[t * LDBU + 32 + k0];
            floatx4 h1 = *(const floatx4*)&bu[t * LDBU + 32 + k0 + 4];
            accY[nt] = __builtin_amdgcn_mfma_f32_16x16x32_bf16(cf0, cvt8(g0, g1), accY[nt], 0, 0, 0);
            accY[nt] = __builtin_amdgcn_mfma_f32_16x16x32_bf16(cf1, cvt8(h0, h1), accY[nt], 0, 0, 0);
        }
        __syncthreads();
        cur = nxt;
    }

    // epilogue: += D*u (direct global D frags), store y
    const bf16x8 df0 = *(const bf16x8*)(Dws + (size_t)(w * 16 + row16) * MI + quad * 8);
    const bf16x8 df1 = *(const bf16x8*)(Dws + (size_t)(w * 16 + row16) * MI + 32 + quad * 8);
#pragma unroll
    for (int nt = 0; nt < 4; ++nt) {
        const int t = nt * 16 + row16;
        accY[nt] = __builtin_amdgcn_mfma_f32_16x16x32_bf16(df0, ufr0[nt], accY[nt], 0, 0, 0);
        accY[nt] = __builtin_amdgcn_mfma_f32_16x16x32_bf16(df1, ufr1[nt], accY[nt], 0, 0, 0);
        const int p0 = w * 16 + quad * 4;
        *(floatx4*)(y + ((size_t)b * SEQ + t0 + t) * PO + p0) = accY[nt];
    }
}

// ---------------------------------------------------------------------------
// s[b][t] = sum_{j=0..t} h[j] f[b][t-j]
// ---------------------------------------------------------------------------
__global__ void __launch_bounds__(256) sconv_kernel(const float* __restrict__ fbuf,
                                                    const float* __restrict__ hbuf,
                                                    float* __restrict__ sbuf) {
    __shared__ float f_l[SEQ];
    __shared__ float h_lc[SEQ + 8];
    __shared__ float part[4][TB];
    const int blk = blockIdx.x, b = blockIdx.y, tid = threadIdx.x;
    const int t0 = blk * TB;
    const int len = t0 + TB;
    {
        const float4* fs = (const float4*)(fbuf + (size_t)b * SEQ);
        const float4* hs = (const float4*)hbuf;
        for (int i = tid; i < len / 4; i += 256) {
            ((float4*)f_l)[i] = fs[i];
            ((float4*)h_lc)[i] = hs[i];
        }
    }
    __syncthreads();
    const int dt = tid & 63, grp = tid >> 6;
    const int t = t0 + dt;
    float acc = 0.f;
    for (int j4 = grp * 4; j4 <= t; j4 += 16) {
        const float4 hv = *(const float4*)&h_lc[j4];
        if (j4 + 0 <= t) acc += hv.x * f_l[t - j4 - 0];
        if (j4 + 1 <= t) acc += hv.y * f_l[t - j4 - 1];
        if (j4 + 2 <= t) acc += hv.z * f_l[t - j4 - 2];
        if (j4 + 3 <= t) acc += hv.w * f_l[t - j4 - 3];
    }
    part[grp][dt] = acc;
    __syncthreads();
    if (tid < TB) {
        sbuf[(size_t)b * SEQ + t0 + tid] =
            part[0][tid] + part[1][tid] + part[2][tid] + part[3][tid];
    }
}

// ---------------------------------------------------------------------------
// corr (MFMA, direct global q-frags, double-buffered Sw, 1 barrier/chunk):
// y[b,t,p] -= sum_j qT[p][j] * s[b, t-1-j]
// ---------------------------------------------------------------------------
__global__ void __launch_bounds__(256) corr_kernel(
    const float* __restrict__ sbuf, const unsigned short* __restrict__ qT,
    float* __restrict__ y) {
    __shared__ float s_l[NS + TB];
    __shared__ unsigned short Sw[2][TB * LDU];
    const int blk = blockIdx.x, b = blockIdx.y, tid = threadIdx.x;
    const int t0 = blk * TB;
    const int lane = tid & 63, w = tid >> 6;
    const int row16 = lane & 15, quad = lane >> 4;
    for (int idx = tid; idx < NS + TB; idx += 256) {
        const int t = t0 - NS + idx;
        s_l[idx] = (t >= 0) ? sbuf[(size_t)b * SEQ + t] : 0.f;
    }
    floatx4 acc[4];
#pragma unroll
    for (int nt = 0; nt < 4; ++nt) acc[nt] = (floatx4){0.f, 0.f, 0.f, 0.f};
    __syncthreads();

    for (int ch = 0; ch < NCH; ++ch) {
        const int buf = ch & 1;
        const bf16x8 qf0 = *(const bf16x8*)(qT + (size_t)(w * 16 + row16) * NS + ch * CH + quad * 8);
        const bf16x8 qf1 = *(const bf16x8*)(qT + (size_t)(w * 16 + row16) * NS + ch * CH + 32 + quad * 8);
        {
            const int r = tid >> 2, c0 = (tid & 3) * 16;
            unsigned short tmp[16];
            const int base = 511 + r - ch * CH - c0;
#pragma unroll
            for (int jj = 0; jj < 16; ++jj) tmp[jj] = f2bf(s_l[base - jj]);
            *(uint4*)&Sw[buf][r * LDU + c0]     = *(uint4*)&tmp[0];
            *(uint4*)&Sw[buf][r * LDU + c0 + 8] = *(uint4*)&tmp[8];
        }
        __syncthreads();
#pragma unroll
        for (int nt = 0; nt < 4; ++nt) {
            const int t = nt * 16 + row16;
            bf16x8 s0 = *(const bf16x8*)&Sw[buf][t * LDU + quad * 8];
            bf16x8 s1 = *(const bf16x8*)&Sw[buf][t * LDU + 32 + quad * 8];
            acc[nt] = __builtin_amdgcn_mfma_f32_16x16x32_bf16(qf0, s0, acc[nt], 0, 0, 0);
            acc[nt] = __builtin_amdgcn_mfma_f32_16x16x32_bf16(qf1, s1, acc[nt], 0, 0, 0);
        }
        // no trailing barrier: next chunk writes the other Sw buffer.
    }
#pragma unroll
    for (int nt = 0; nt < 4; ++nt) {
        const int t = nt * 16 + row16;
        const int p0 = w * 16 + quad * 4;
        float* yp = y + ((size_t)b * SEQ + t0 + t) * PO + p0;
        floatx4 old = *(const floatx4*)yp;
        *(floatx4*)yp = old - acc[nt];
    }
}

// ---------------------------------------------------------------------------
extern "C" void kernel_launch(void* const* d_in, const int* in_sizes, int n_in,
                              void* d_out, int out_size, void* d_ws,
                              size_t ws_size, hipStream_t stream) {
    const float* u  = (const float*)d_in[0];
    const float* a  = (const float*)d_in[1];
    const float* B  = (const float*)d_in[2];
    const float* Cm = (const float*)d_in[3];
    const float* Dm = (const float*)d_in[4];
    float* y = (float*)d_out;

    char* ws = (char*)d_ws;
    unsigned short* Bws = (unsigned short*)ws;                  ws += NS * MI * 2;
    unsigned short* Cws = (unsigned short*)ws;                  ws += PO * NS * 2;
    unsigned short* Dws = (unsigned short*)ws;                  ws += PO * MI * 2;
    unsigned short* qTw = (unsigned short*)ws;                  ws += PO * NS * 2;
    unsigned short* ubf = (unsigned short*)ws;                  ws += (size_t)NB * SEQ * MI * 2;
    unsigned short* Bft = (unsigned short*)ws;                  ws += (size_t)NS * 4096 * 2;
    float* Sbuf = (float*)ws;                                   ws += (size_t)NB * NTB * NS * 4;
    float* Rbuf = (float*)ws;                                   ws += (size_t)NB * NTB * NS * 4;
    float* fbuf = (float*)ws;                                   ws += (size_t)NB * SEQ * 4;
    float* sbuf = (float*)ws;                                   ws += (size_t)NB * SEQ * 4;
    float* hbuf = (float*)ws;                                   // 2048 floats (~17.5 MB total)

    prep_all_kernel<<<dim3(2896), dim3(256), 0, stream>>>(
        u, B, Cm, Dm, a, ubf, Bft, Bws, Cws, Dws, qTw);
    sgemm_kernel<<<dim3(8, 16), dim3(256), 0, stream>>>(ubf, Bft, Sbuf);
    scan_himp_kernel<<<dim3(NB + 1), dim3(1024), 0, stream>>>(Sbuf, Rbuf, a, hbuf);
    ytile_kernel<<<dim3(NTB, NB), dim3(256), 0, stream>>>(
        ubf, Bws, Cws, Dws, Rbuf, fbuf, y);
    sconv_kernel<<<dim3(NTB, NB), dim3(256), 0, stream>>>(fbuf, hbuf, sbuf);
    corr_kernel<<<dim3(NTB, NB), dim3(256), 0, stream>>>(sbuf, qTw, y);
}

// Round 7
// 279.760 us; speedup vs baseline: 1.8382x; 1.0225x over previous
//
#include <hip/hip_runtime.h>

// Problem constants
#define SEQ  2048
#define NB   32
#define NS   512
#define MI   64   // M_IN
#define PO   64   // P_OUT
#define TB   64   // t-block
#define NTB  32   // SEQ/TB
#define CH   64   // i-chunk
#define NCH  8    // NS/CH
#define LDU  72   // u_b / Gb / Sw stride (ushort)
#define LDBU 68   // bu stride (float)
#define SG_LDA 72 // sgemm LDS stride (ushort)

typedef __attribute__((ext_vector_type(8))) __bf16 bf16x8;
typedef __attribute__((ext_vector_type(4))) float  floatx4;

__device__ inline unsigned short f2bf(float f) {
    unsigned u = __builtin_bit_cast(unsigned, f);
    u += 0x7fff + ((u >> 16) & 1);           // RNE
    return (unsigned short)(u >> 16);
}

// ---------------------------------------------------------------------------
// Fused prep: [0,2048) u->bf16 | [2048,2560) BflatT | [2560,2624) q
// | [2624,2896) B/C/D -> bf16
// ---------------------------------------------------------------------------
__global__ void __launch_bounds__(256) prep_all_kernel(
    const float* __restrict__ u, const float* __restrict__ B,
    const float* __restrict__ C, const float* __restrict__ D,
    const float* __restrict__ a,
    unsigned short* __restrict__ ubf, unsigned short* __restrict__ BflatT,
    unsigned short* __restrict__ Bws, unsigned short* __restrict__ Cws,
    unsigned short* __restrict__ Dws, unsigned short* __restrict__ qT) {
    __shared__ float a_ext[1024];
    const int bx = blockIdx.x, tid = threadIdx.x;
    if (bx < 2048) {                       // ---- uconv
        const size_t base = ((size_t)bx * 256 + tid) * 8;
        float4 f0 = *(const float4*)(u + base);
        float4 f1 = *(const float4*)(u + base + 4);
        unsigned short tmp[8];
        tmp[0] = f2bf(f0.x); tmp[1] = f2bf(f0.y); tmp[2] = f2bf(f0.z); tmp[3] = f2bf(f0.w);
        tmp[4] = f2bf(f1.x); tmp[5] = f2bf(f1.y); tmp[6] = f2bf(f1.z); tmp[7] = f2bf(f1.w);
        *(uint4*)(ubf + base) = *(uint4*)&tmp[0];
    } else if (bx < 2560) {                // ---- BflatT[i][(j,m)] = B[i-j,m]
        const int i = bx - 2048;
        for (int r = 0; r < 2; ++r) {
            const int id = tid + r * 256;
            const int j = id >> 3, q8 = (id & 7) * 8;
            unsigned short tmp[8];
            if (i >= j) {
                const float4 f0 = *(const float4*)(B + (size_t)(i - j) * MI + q8);
                const float4 f1 = *(const float4*)(B + (size_t)(i - j) * MI + q8 + 4);
                tmp[0] = f2bf(f0.x); tmp[1] = f2bf(f0.y); tmp[2] = f2bf(f0.z); tmp[3] = f2bf(f0.w);
                tmp[4] = f2bf(f1.x); tmp[5] = f2bf(f1.y); tmp[6] = f2bf(f1.z); tmp[7] = f2bf(f1.w);
            } else {
#pragma unroll
                for (int z = 0; z < 8; ++z) tmp[z] = 0;
            }
            *(uint4*)(BflatT + (size_t)i * 4096 + j * 64 + q8) = *(uint4*)&tmp[0];
        }
    } else if (bx < 2624) {                // ---- q: qT[p][j]
        const int p = bx - 2560;
        for (int x = tid; x < 1024; x += 256) a_ext[x] = (x < NS) ? a[x] : 0.f;
        __syncthreads();
        const int j0 = tid, j1 = tid + 256;
        float acc0 = 0.f, acc1 = 0.f;
        const float4* crow = (const float4*)(C + (size_t)p * NS);
        for (int i4 = 0; i4 < NS / 4; ++i4) {
            const float4 cv = crow[i4];
            const int base = 511 - i4 * 4;
            acc0 += cv.x * a_ext[base + j0]     + cv.y * a_ext[base - 1 + j0] +
                    cv.z * a_ext[base - 2 + j0] + cv.w * a_ext[base - 3 + j0];
            acc1 += cv.x * a_ext[base + j1]     + cv.y * a_ext[base - 1 + j1] +
                    cv.z * a_ext[base - 2 + j1] + cv.w * a_ext[base - 3 + j1];
        }
        qT[(size_t)p * NS + j0] = f2bf(acc0);
        qT[(size_t)p * NS + j1] = f2bf(acc1);
    } else {                               // ---- B/C/D bf16 cvt
        const int idx = (bx - 2624) * 256 + tid;
        const int nB = NS * MI, nC = PO * NS, nD = PO * MI;
        if (idx < nB) Bws[idx] = f2bf(B[idx]);
        else if (idx < nB + nC) Cws[idx - nB] = f2bf(C[idx - nB]);
        else if (idx < nB + nC + nD) Dws[idx - nB - nC] = f2bf(D[idx - nB - nC]);
    }
}

// ---------------------------------------------------------------------------
// S-GEMM: S[(b,k), i] = sum_{(j,m)} BflatT[i][(j,m)] * u[b, k*64+63-j, m]
// Grid (8 i-blocks, 32 batches): 256 WGs -> one per CU.
// ---------------------------------------------------------------------------
__global__ void __launch_bounds__(256) sgemm_kernel(const unsigned short* __restrict__ ubf,
                                                    const unsigned short* __restrict__ BflatT,
                                                    float* __restrict__ Sbuf) {
    __shared__ unsigned short A_l[4 * 64 * SG_LDA];   // 36.9 KB
    __shared__ unsigned short U_l[4 * 32 * SG_LDA];   // 18.4 KB
    const int ib = blockIdx.x, b = blockIdx.y;
    const int tid = threadIdx.x, lane = tid & 63, w = tid >> 6;
    const int row16 = lane & 15, quad = lane >> 4;
    const int i0 = ib * 64;
    floatx4 acc[2];
#pragma unroll
    for (int ns = 0; ns < 2; ++ns) acc[ns] = (floatx4){0.f, 0.f, 0.f, 0.f};

    for (int jg = 0; jg < 16; ++jg) {
#pragma unroll
        for (int r = 0; r < 8; ++r) {
            const int id = tid + r * 256;        // 0..2047
            const int row = id >> 5;             // 0..63 (i row)
            const int jj = (id >> 3) & 3, q8 = (id & 7) * 8;
            const int j = jg * 4 + jj;
            *(uint4*)&A_l[(jj * 64 + row) * SG_LDA + q8] =
                *(const uint4*)(BflatT + (size_t)(i0 + row) * 4096 + j * 64 + q8);
        }
#pragma unroll
        for (int r = 0; r < 4; ++r) {
            const int id = tid + r * 256;        // 0..1023
            const int n = id >> 5;               // 0..31 (k-tile)
            const int jj = (id >> 3) & 3, q8 = (id & 7) * 8;
            const int j = jg * 4 + jj;
            *(uint4*)&U_l[(jj * 32 + n) * SG_LDA + q8] =
                *(const uint4*)(ubf + ((size_t)b * SEQ + n * 64 + 63 - j) * MI + q8);
        }
        __syncthreads();
#pragma unroll
        for (int jj = 0; jj < 4; ++jj) {
#pragma unroll
            for (int mk = 0; mk < 2; ++mk) {
                const bf16x8 av = *(const bf16x8*)
                    &A_l[(jj * 64 + w * 16 + row16) * SG_LDA + mk * 32 + quad * 8];
#pragma unroll
                for (int ns = 0; ns < 2; ++ns) {
                    const bf16x8 bv = *(const bf16x8*)
                        &U_l[(jj * 32 + ns * 16 + row16) * SG_LDA + mk * 32 + quad * 8];
                    acc[ns] = __builtin_amdgcn_mfma_f32_16x16x32_bf16(av, bv, acc[ns], 0, 0, 0);
                }
            }
        }
        __syncthreads();
    }
#pragma unroll
    for (int ns = 0; ns < 2; ++ns) {
        const int n = ns * 16 + row16;           // k-tile 0..31
        float* dst = Sbuf + ((size_t)b * NTB + n) * NS + i0 + w * 16 + quad * 4;
        *(floatx4*)dst = acc[ns];
    }
}

// ---------------------------------------------------------------------------
// Fused (1024 threads): blocks 0..31 = block-carry scan (per batch);
// block 32 = impulse response h (fixed-trip, register-cached taps).
// ---------------------------------------------------------------------------
__global__ void __launch_bounds__(1024) scan_himp_kernel(const float* __restrict__ Sbuf,
                                                         float* __restrict__ Rbuf,
                                                         const float* __restrict__ a,
                                                         float* __restrict__ hbuf) {
    __shared__ __align__(16) char smem[69632];
    const int tid = threadIdx.x;
    if (blockIdx.x < NB) {
        // ---------------- scan ----------------
        float* S_l = (float*)smem;                 // 64 KB
        float* Rc  = (float*)(smem + 65536);
        const int b = blockIdx.x;
        const float4* src = (const float4*)(Sbuf + (size_t)b * NTB * NS);
        for (int k = tid; k < NTB * NS / 4; k += 1024) ((float4*)S_l)[k] = src[k];
        if (tid < 128) ((float4*)Rc)[tid] = make_float4(0.f, 0.f, 0.f, 0.f);
        __syncthreads();
        int cur = 0;
        for (int k = 0; k < NTB; ++k) {
            if (tid < 128) {
                const int i0 = tid * 4;
                float4 r = *(const float4*)&Rc[cur * NS + i0];
                *(float4*)(Rbuf + ((size_t)b * NTB + k) * NS + i0) = r;
                float4 s = *(const float4*)&S_l[k * NS + i0];
                float4 rp = (i0 >= TB) ? *(const float4*)&Rc[cur * NS + i0 - TB]
                                       : make_float4(0.f, 0.f, 0.f, 0.f);
                float4 nv = make_float4(s.x + rp.x, s.y + rp.y, s.z + rp.z, s.w + rp.w);
                *(float4*)&Rc[(cur ^ 1) * NS + i0] = nv;
            }
            __syncthreads();
            cur ^= 1;
        }
    } else {
        // ---------------- himp ----------------
        float* a_l     = (float*)smem;                  // 640 floats (zero-pad)
        float* h_ext   = (float*)(smem + 2560);         // 512 zeros + h[0:2048]
        float* part    = (float*)(smem + 12800);        // 16 * 128
        float* rhs_ext = (float*)(smem + 20992);        // 128 zeros + 128
        const int kk = tid & 63, grp = tid >> 6;        // 16 groups of 64

        for (int x = tid; x < 640; x += 1024) a_l[x] = (x < NS) ? a[x] : 0.f;
        for (int x = tid; x < 512; x += 1024) h_ext[x] = 0.f;
        if (tid < 128) rhs_ext[tid] = 0.f;
        __syncthreads();

        float a0r[32], a1r[32];
#pragma unroll
        for (int i = 0; i < 32; ++i) a0r[i] = a_l[kk + grp * 32 + i];
#pragma unroll
        for (int i = 0; i < 32; ++i) a1r[i] = a_l[kk + 64 + grp * 32 + i];

        if (tid < 64) {
            if (tid == 0) h_ext[512] = 1.f;
            for (int t = 1; t < 64; ++t) {
                float pr = (tid < t) ? a_l[tid] * h_ext[512 + t - 1 - tid] : 0.f;
#pragma unroll
                for (int off = 32; off; off >>= 1) pr += __shfl_xor(pr, off);
                if (tid == 0) h_ext[512 + t] = -pr;
            }
        }
        __syncthreads();

        {   // doubling 64 -> 128
            const int t0 = 64;
            float acc0 = 0.f;
#pragma unroll
            for (int m = 0; m < 8; ++m) {
                const float4 hv = *(const float4*)&h_ext[512 + t0 - grp * 32 - 4 - 4 * m];
                acc0 += a0r[4 * m + 0] * hv.w + a0r[4 * m + 1] * hv.z +
                        a0r[4 * m + 2] * hv.y + a0r[4 * m + 3] * hv.x;
            }
            part[grp * 128 + kk] = acc0;
            __syncthreads();
            if (tid < 64) {
                float r = 0.f;
#pragma unroll
                for (int g = 0; g < 16; ++g) r += part[g * 128 + tid];
                rhs_ext[128 + tid] = -r;
            }
            __syncthreads();
            if (tid < 64) {
                float s0 = 0.f, s1 = 0.f, s2 = 0.f, s3 = 0.f;
#pragma unroll
                for (int j = 0; j < 64; j += 4) {
                    const float4 h4 = *(const float4*)&h_ext[512 + j];
                    s0 += h4.x * rhs_ext[128 + tid - j];
                    s1 += h4.y * rhs_ext[128 + tid - j - 1];
                    s2 += h4.z * rhs_ext[128 + tid - j - 2];
                    s3 += h4.w * rhs_ext[128 + tid - j - 3];
                }
                h_ext[512 + t0 + tid] = s0 + s1 + s2 + s3;
            }
            __syncthreads();
        }

        for (int t0 = 128; t0 < SEQ; t0 += 128) {
            float acc0 = 0.f, acc1 = 0.f;
#pragma unroll
            for (int m = 0; m < 8; ++m) {
                const float4 hv = *(const float4*)&h_ext[512 + t0 - grp * 32 - 4 - 4 * m];
                acc0 += a0r[4 * m + 0] * hv.w + a0r[4 * m + 1] * hv.z +
                        a0r[4 * m + 2] * hv.y + a0r[4 * m + 3] * hv.x;
                acc1 += a1r[4 * m + 0] * hv.w + a1r[4 * m + 1] * hv.z +
                        a1r[4 * m + 2] * hv.y + a1r[4 * m + 3] * hv.x;
            }
            part[grp * 128 + kk]      = acc0;
            part[grp * 128 + kk + 64] = acc1;
            __syncthreads();
            if (tid < 128) {
                float r = 0.f;
#pragma unroll
                for (int g = 0; g < 16; ++g) r += part[g * 128 + tid];
                rhs_ext[128 + tid] = -r;
            }
            __syncthreads();
            if (tid < 128) {
                float s0 = 0.f, s1 = 0.f, s2 = 0.f, s3 = 0.f;
#pragma unroll
                for (int j = 0; j < 128; j += 4) {
                    const float4 h4 = *(const float4*)&h_ext[512 + j];
                    s0 += h4.x * rhs_ext[128 + tid - j];
                    s1 += h4.y * rhs_ext[128 + tid - j - 1];
                    s2 += h4.z * rhs_ext[128 + tid - j - 2];
                    s3 += h4.w * rhs_ext[128 + tid - j - 3];
                }
                h_ext[512 + t0 + tid] = s0 + s1 + s2 + s3;
            }
            __syncthreads();
        }
        for (int i = tid; i < SEQ; i += 1024) hbuf[i] = h_ext[512 + i];
    }
}

// ---------------------------------------------------------------------------
// ytile (MFMA): per (t-block, batch). Bu via MFMA; SEGMENTED parallel diagonal
// cumsum (2 segs x 127 diags, all reads independent); G stored bf16 -> phase B
// reads bf16x8 directly (no cvt on MFMA path); y = C*G + D*u; emit f.
// ---------------------------------------------------------------------------
__global__ void __launch_bounds__(256) ytile_kernel(
    const unsigned short* __restrict__ ubf, const unsigned short* __restrict__ Bws,
    const unsigned short* __restrict__ Cws, const unsigned short* __restrict__ Dws,
    const float* __restrict__ Rbuf, float* __restrict__ fbuf, float* __restrict__ y) {
    __shared__ unsigned short u_b[TB * LDU];   // 9.2 KB
    __shared__ float bu[TB * LDBU];            // 17.4 KB (Bu fp32, read-only after A)
    __shared__ unsigned short Gb[TB * LDU];    // 9.2 KB (G bf16)
    __shared__ float colBuf[2][TB];
    __shared__ float carryB[128];
    __shared__ float part0[128];

    const int blk = blockIdx.x, b = blockIdx.y;
    const int t0 = blk * TB;
    const int tid = threadIdx.x;
    const int lane = tid & 63, w = tid >> 6;
    const int row16 = lane & 15, quad = lane >> 4;

    // stage u tile (bf16, pre-converted)
#pragma unroll
    for (int r = 0; r < 2; ++r) {
        const int id = tid + r * 256;
        const int t = id >> 3, q8 = (id & 7) * 8;
        *(uint4*)&u_b[t * LDU + q8] =
            *(const uint4*)(ubf + ((size_t)b * SEQ + t0 + t) * MI + q8);
    }
    if (tid < TB) colBuf[0][tid] = 0.f;

    floatx4 accY[4];
#pragma unroll
    for (int nt = 0; nt < 4; ++nt) accY[nt] = (floatx4){0.f, 0.f, 0.f, 0.f};
    __syncthreads();

    // preload u B-operand frags once
    bf16x8 ufr0[4], ufr1[4];
#pragma unroll
    for (int nt = 0; nt < 4; ++nt) {
        const int t = nt * 16 + row16;
        ufr0[nt] = *(const bf16x8*)&u_b[t * LDU + quad * 8];
        ufr1[nt] = *(const bf16x8*)&u_b[t * LDU + 32 + quad * 8];
    }

    const int d = tid & 127, sgm = tid >> 7;   // walk mapping: diag d, segment sgm

    int cur = 0;
    for (int ch = 0; ch < NCH; ++ch) {
        const bf16x8 bf0 = *(const bf16x8*)(Bws + (size_t)(ch * CH + w * 16 + row16) * MI + quad * 8);
        const bf16x8 bf1 = *(const bf16x8*)(Bws + (size_t)(ch * CH + w * 16 + row16) * MI + 32 + quad * 8);
        const bf16x8 cf0 = *(const bf16x8*)(Cws + (size_t)(w * 16 + row16) * NS + ch * CH + quad * 8);
        const bf16x8 cf1 = *(const bf16x8*)(Cws + (size_t)(w * 16 + row16) * NS + ch * CH + 32 + quad * 8);

        // phase A: Bu chunk -> bu (fp32)
#pragma unroll
        for (int nt = 0; nt < 4; ++nt) {
            floatx4 dacc = {0.f, 0.f, 0.f, 0.f};
            dacc = __builtin_amdgcn_mfma_f32_16x16x32_bf16(bf0, ufr0[nt], dacc, 0, 0, 0);
            dacc = __builtin_amdgcn_mfma_f32_16x16x32_bf16(bf1, ufr1[nt], dacc, 0, 0, 0);
            const int t = nt * 16 + row16;
            *(floatx4*)&bu[t * LDBU + w * 16 + quad * 4] = dacc;
        }
        __syncthreads();

        // ---- walk step 1: s=0 fetch carries; s=1 segment-0 sums ----
        const int nxt = cur ^ 1;
        if (d < 127) {
            const int cl = d - 63;
            if (sgm == 0) {
                float carry;
                if (cl < 0) carry = colBuf[cur][-cl - 1];
                else {
                    const int gi = ch * CH + cl;
                    carry = (gi >= 1) ? Rbuf[((size_t)b * NTB + blk) * NS + gi - 1] : 0.f;
                }
                carryB[d] = carry;
            } else {
                float sgs = 0.f;
#pragma unroll
                for (int t = 0; t < 32; ++t) {
                    const int il = cl + t;
                    if (il >= 0 && il < CH) sgs += bu[t * LDBU + il];
                }
                part0[d] = sgs;
            }
        }
        __syncthreads();

        // ---- walk step 2: apply prefix, write G as bf16; s=1 emits totals ----
        if (d < 127) {
            const int cl = d - 63;
            float run = carryB[d] + (sgm ? part0[d] : 0.f);
            const int tb0 = sgm * 32;
#pragma unroll
            for (int ti = 0; ti < 32; ++ti) {
                const int t = tb0 + ti;
                const int il = cl + t;
                if (il >= 0 && il < CH) {
                    run += bu[t * LDBU + il];
                    Gb[t * LDU + il] = f2bf(run);
                }
            }
            if (sgm && cl >= 0) {
                if (ch == NCH - 1) fbuf[(size_t)b * SEQ + t0 + 63 - cl] = run;
                else if (cl > 0) colBuf[nxt][63 - cl] = run;
            }
        }
        __syncthreads();

        // phase B: accY += C[:,chunk] * G[chunk]  (bf16 direct)
#pragma unroll
        for (int nt = 0; nt < 4; ++nt) {
            const int t = nt * 16 + row16;
            bf16x8 g0 = *(const bf16x8*)&Gb[t * LDU + quad * 8];
            bf16x8 g1 = *(const bf16x8*)&Gb[t * LDU + 32 + quad * 8];
            accY[nt] = __builtin_amdgcn_mfma_f32_16x16x32_bf16(cf0, g0, accY[nt], 0, 0, 0);
            accY[nt] = __builtin_amdgcn_mfma_f32_16x16x32_bf16(cf1, g1, accY[nt], 0, 0, 0);
        }
        __syncthreads();
        cur = nxt;
    }

    // epilogue: += D*u, store y
    const bf16x8 df0 = *(const bf16x8*)(Dws + (size_t)(w * 16 + row16) * MI + quad * 8);
    const bf16x8 df1 = *(const bf16x8*)(Dws + (size_t)(w * 16 + row16) * MI + 32 + quad * 8);
#pragma unroll
    for (int nt = 0; nt < 4; ++nt) {
        const int t = nt * 16 + row16;
        accY[nt] = __builtin_amdgcn_mfma_f32_16x16x32_bf16(df0, ufr0[nt], accY[nt], 0, 0, 0);
        accY[nt] = __builtin_amdgcn_mfma_f32_16x16x32_bf16(df1, ufr1[nt], accY[nt], 0, 0, 0);
        const int p0 = w * 16 + quad * 4;
        *(floatx4*)(y + ((size_t)b * SEQ + t0 + t) * PO + p0) = accY[nt];
    }
}

// ---------------------------------------------------------------------------
// s[b][t] = sum_{j=0..t} h[j] f[b][t-j]
// ---------------------------------------------------------------------------
__global__ void __launch_bounds__(256) sconv_kernel(const float* __restrict__ fbuf,
                                                    const float* __restrict__ hbuf,
                                                    float* __restrict__ sbuf) {
    __shared__ float f_l[SEQ];
    __shared__ float h_lc[SEQ + 8];
    __shared__ float part[4][TB];
    const int blk = blockIdx.x, b = blockIdx.y, tid = threadIdx.x;
    const int t0 = blk * TB;
    const int len = t0 + TB;
    {
        const float4* fs = (const float4*)(fbuf + (size_t)b * SEQ);
        const float4* hs = (const float4*)hbuf;
        for (int i = tid; i < len / 4; i += 256) {
            ((float4*)f_l)[i] = fs[i];
            ((float4*)h_lc)[i] = hs[i];
        }
    }
    __syncthreads();
    const int dt = tid & 63, grp = tid >> 6;
    const int t = t0 + dt;
    float acc = 0.f;
    for (int j4 = grp * 4; j4 <= t; j4 += 16) {
        const float4 hv = *(const float4*)&h_lc[j4];
        if (j4 + 0 <= t) acc += hv.x * f_l[t - j4 - 0];
        if (j4 + 1 <= t) acc += hv.y * f_l[t - j4 - 1];
        if (j4 + 2 <= t) acc += hv.z * f_l[t - j4 - 2];
        if (j4 + 3 <= t) acc += hv.w * f_l[t - j4 - 3];
    }
    part[grp][dt] = acc;
    __syncthreads();
    if (tid < TB) {
        sbuf[(size_t)b * SEQ + t0 + tid] =
            part[0][tid] + part[1][tid] + part[2][tid] + part[3][tid];
    }
}

// ---------------------------------------------------------------------------
// corr (MFMA, direct global q-frags, double-buffered Sw, 1 barrier/chunk):
// y[b,t,p] -= sum_j qT[p][j] * s[b, t-1-j]
// ---------------------------------------------------------------------------
__global__ void __launch_bounds__(256) corr_kernel(
    const float* __restrict__ sbuf, const unsigned short* __restrict__ qT,
    float* __restrict__ y) {
    __shared__ float s_l[NS + TB];
    __shared__ unsigned short Sw[2][TB * LDU];
    const int blk = blockIdx.x, b = blockIdx.y, tid = threadIdx.x;
    const int t0 = blk * TB;
    const int lane = tid & 63, w = tid >> 6;
    const int row16 = lane & 15, quad = lane >> 4;
    for (int idx = tid; idx < NS + TB; idx += 256) {
        const int t = t0 - NS + idx;
        s_l[idx] = (t >= 0) ? sbuf[(size_t)b * SEQ + t] : 0.f;
    }
    floatx4 acc[4];
#pragma unroll
    for (int nt = 0; nt < 4; ++nt) acc[nt] = (floatx4){0.f, 0.f, 0.f, 0.f};
    __syncthreads();

    for (int ch = 0; ch < NCH; ++ch) {
        const int buf = ch & 1;
        const bf16x8 qf0 = *(const bf16x8*)(qT + (size_t)(w * 16 + row16) * NS + ch * CH + quad * 8);
        const bf16x8 qf1 = *(const bf16x8*)(qT + (size_t)(w * 16 + row16) * NS + ch * CH + 32 + quad * 8);
        {
            const int r = tid >> 2, c0 = (tid & 3) * 16;
            unsigned short tmp[16];
            const int base = 511 + r - ch * CH - c0;
#pragma unroll
            for (int jj = 0; jj < 16; ++jj) tmp[jj] = f2bf(s_l[base - jj]);
            *(uint4*)&Sw[buf][r * LDU + c0]     = *(uint4*)&tmp[0];
            *(uint4*)&Sw[buf][r * LDU + c0 + 8] = *(uint4*)&tmp[8];
        }
        __syncthreads();
#pragma unroll
        for (int nt = 0; nt < 4; ++nt) {
            const int t = nt * 16 + row16;
            bf16x8 s0 = *(const bf16x8*)&Sw[buf][t * LDU + quad * 8];
            bf16x8 s1 = *(const bf16x8*)&Sw[buf][t * LDU + 32 + quad * 8];
            acc[nt] = __builtin_amdgcn_mfma_f32_16x16x32_bf16(qf0, s0, acc[nt], 0, 0, 0);
            acc[nt] = __builtin_amdgcn_mfma_f32_16x16x32_bf16(qf1, s1, acc[nt], 0, 0, 0);
        }
    }
#pragma unroll
    for (int nt = 0; nt < 4; ++nt) {
        const int t = nt * 16 + row16;
        const int p0 = w * 16 + quad * 4;
        float* yp = y + ((size_t)b * SEQ + t0 + t) * PO + p0;
        floatx4 old = *(const floatx4*)yp;
        *(floatx4*)yp = old - acc[nt];
    }
}

// ---------------------------------------------------------------------------
extern "C" void kernel_launch(void* const* d_in, const int* in_sizes, int n_in,
                              void* d_out, int out_size, void* d_ws,
                              size_t ws_size, hipStream_t stream) {
    const float* u  = (const float*)d_in[0];
    const float* a  = (const float*)d_in[1];
    const float* B  = (const float*)d_in[2];
    const float* Cm = (const float*)d_in[3];
    const float* Dm = (const float*)d_in[4];
    float* y = (float*)d_out;

    char* ws = (char*)d_ws;
    unsigned short* Bws = (unsigned short*)ws;                  ws += NS * MI * 2;
    unsigned short* Cws = (unsigned short*)ws;                  ws += PO * NS * 2;
    unsigned short* Dws = (unsigned short*)ws;                  ws += PO * MI * 2;
    unsigned short* qTw = (unsigned short*)ws;                  ws += PO * NS * 2;
    unsigned short* ubf = (unsigned short*)ws;                  ws += (size_t)NB * SEQ * MI * 2;
    unsigned short* Bft = (unsigned short*)ws;                  ws += (size_t)NS * 4096 * 2;
    float* Sbuf = (float*)ws;                                   ws += (size_t)NB * NTB * NS * 4;
    float* Rbuf = (float*)ws;                                   ws += (size_t)NB * NTB * NS * 4;
    float* fbuf = (float*)ws;                                   ws += (size_t)NB * SEQ * 4;
    float* sbuf = (float*)ws;                                   ws += (size_t)NB * SEQ * 4;
    float* hbuf = (float*)ws;                                   // 2048 floats (~17.5 MB total)

    prep_all_kernel<<<dim3(2896), dim3(256), 0, stream>>>(
        u, B, Cm, Dm, a, ubf, Bft, Bws, Cws, Dws, qTw);
    sgemm_kernel<<<dim3(8, 32), dim3(256), 0, stream>>>(ubf, Bft, Sbuf);
    scan_himp_kernel<<<dim3(NB + 1), dim3(1024), 0, stream>>>(Sbuf, Rbuf, a, hbuf);
    ytile_kernel<<<dim3(NTB, NB), dim3(256), 0, stream>>>(
        ubf, Bws, Cws, Dws, Rbuf, fbuf, y);
    sconv_kernel<<<dim3(NTB, NB), dim3(256), 0, stream>>>(fbuf, hbuf, sbuf);
    corr_kernel<<<dim3(NTB, NB), dim3(256), 0, stream>>>(sbuf, qTw, y);
}